// Round 5
// baseline (616.405 us; speedup 1.0000x reference)
//
#include <hip/hip_runtime.h>
#include <hip/hip_bf16.h>
#include <math.h>

typedef __bf16 bf16x8 __attribute__((ext_vector_type(8)));
typedef float  f32x4  __attribute__((ext_vector_type(4)));
typedef float  f32x16 __attribute__((ext_vector_type(16)));
typedef unsigned short ushort_t;
typedef ushort_t us4 __attribute__((ext_vector_type(4)));

#define MFMA16(a, b, c) __builtin_amdgcn_mfma_f32_16x16x32_bf16((a), (b), (c), 0, 0, 0)
#define MFMA32(a, b, c) __builtin_amdgcn_mfma_f32_32x32x16_bf16((a), (b), (c), 0, 0, 0)

__device__ __forceinline__ float bf2f(ushort_t h) {
    union { unsigned u; float f; } v; v.u = ((unsigned)h) << 16; return v.f;
}
__device__ __forceinline__ ushort_t f2bf(float x) {
    union { float f; unsigned u; } v; v.f = x;
    unsigned r = v.u + 0x7FFFu + ((v.u >> 16) & 1u);
    return (ushort_t)(r >> 16);
}
// async global->LDS, 16B per lane. LDS dest must be wave-uniform base + lane*16.
__device__ __forceinline__ void gl2lds16(const void* g, void* l) {
    __builtin_amdgcn_global_load_lds((__attribute__((address_space(1))) void*)(g),
                                     (__attribute__((address_space(3))) void*)(l),
                                     16, 0, 0);
}

// ---------------------------------------------------------------------------
// Dtype detector (verified: flag=1 fires, inputs are fp32).
// ---------------------------------------------------------------------------
__global__ __launch_bounds__(256) void detect_kernel(const ushort_t* __restrict__ w, int* flag)
{
    __shared__ int cnt[256];
    const int t = threadIdx.x;
    int c = 0;
    for (int i = t; i < 65536; i += 256) {
        const unsigned hw = w[i];
        const unsigned e = (hw >> 7) & 0xFFu;
        if (e == 0xFFu || (e == 0u && (hw & 0x7Fu) != 0u)) c++;
    }
    cnt[t] = c;
    __syncthreads();
    for (int s = 128; s > 0; s >>= 1) {
        if (t < s) cnt[t] += cnt[t + s];
        __syncthreads();
    }
    if (t == 0) flag[0] = (cnt[0] >= 8) ? 1 : 0;
}

__global__ __launch_bounds__(256) void convert_kernel(const void* __restrict__ src,
                                                      ushort_t* __restrict__ dst,
                                                      int n, const int* __restrict__ flag)
{
    const int i0 = (blockIdx.x * 256 + threadIdx.x) * 8;
    if (i0 + 8 > n) return;
    if (flag[0]) {
        const f32x4 a = *(const f32x4*)((const float*)src + i0);
        const f32x4 b = *(const f32x4*)((const float*)src + i0 + 4);
        ushort_t o[8];
        o[0]=f2bf(a[0]); o[1]=f2bf(a[1]); o[2]=f2bf(a[2]); o[3]=f2bf(a[3]);
        o[4]=f2bf(b[0]); o[5]=f2bf(b[1]); o[6]=f2bf(b[2]); o[7]=f2bf(b[3]);
        *(bf16x8*)(dst + i0) = *(const bf16x8*)o;
    } else {
        *(bf16x8*)(dst + i0) = *(const bf16x8*)((const ushort_t*)src + i0);
    }
}

// ---------------------------------------------------------------------------
// QKV GEMM, C = A * B^T + bias (bf16 in/out).
// ROUND-4 RESTRUCTURE: occupancy + grid tail, not intra-block schedule.
//   Rounds 2/3 (schedule-only edits on the 256x256 / 1-block-per-CU kernel)
//   were neutral at ~28% MfmaUtil: with 1 resident block (2 waves/SIMD, all
//   barrier-locked), barrier/guard stalls cannot be hidden; and 384 blocks on
//   256 CUs = 1.5 rounds -> 25% CU-time idle by construction (MFMA floor 66us,
//   not 41us).
//   Now: tile 128x128, 256 thr / 4 waves (2Mx2N, per-wave 64x64, acc 4x4 = 64
//   AGPR; m97-identical geometry measured 84 arch VGPR -> total ~148).
//   __launch_bounds__(256,3) budget=170 -> no spill, 12 waves/CU.
//   3-slot ring of K-32 chunks (A 8KB + B 8KB = 16KB/chunk, 48KB LDS) ->
//   3 blocks/CU resident: cross-block overlap hides barrier drains (m97/m114
//   mechanism). Grid (48,32) = 1536 blocks = 6 full rounds, zero tail.
// Per phase c: stage chunk c+2 -> slot (c+2)%3 (4 glds ops); read 4 A + 4 B
//   frags of chunk c; 16 MFMA; guard end-of-phase:
//     c <= NC-3: vmcnt(4)  [chunk c+1 ready; 4 younger (c+2's ops) in flight]
//     c == NC-2: vmcnt(0)  [last chunk ready; no younger]
//   then s_barrier. WAR: slot (c+2)%3 held chunk c-1, whose reads completed
//   before the end-of-phase-(c-1) barrier (consumer MFMAs force lgkm drain).
// LDS swizzle (round-0, verified): 16B unit (row,qs) holds k-octet
//   qs ^ ((row>>1)&3), realized by inverse-swizzling the GLOBAL source.
// Accumulation in ascending-k order -> numerics identical to prior rounds.
// ---------------------------------------------------------------------------
__global__ __launch_bounds__(256, 3) void gemm_qkv_bt_bias(
    const ushort_t* __restrict__ A, const ushort_t* __restrict__ B,
    const ushort_t* __restrict__ bias, ushort_t* __restrict__ C,
    int M, int N, int K)
{
    __shared__ __align__(16) ushort_t SM[24576];   // 3 slots x (4096 A + 4096 B) ushorts = 48KB
    const int tid = threadIdx.x;
    const int l = tid & 63, ln = l & 15, q2 = l >> 4;
    const int w = tid >> 6, wm = w >> 1, wn = w & 1;   // 2M x 2N waves
    const int m0 = blockIdx.y * 128, n0 = blockIdx.x * 128;
    const int NC = K >> 5;   // K-32 chunks

#define STG_A(slot, kbase, o) do { \
    const int s_ = (o) * 256 + tid; const int r_ = s_ >> 2; \
    const int q_ = (s_ & 3) ^ ((r_ >> 1) & 3); \
    gl2lds16(A + (size_t)(m0 + r_) * K + (kbase) + q_ * 8, \
             SM + (slot) * 8192 + s_ * 8); } while (0)
#define STG_B(slot, kbase, o) do { \
    const int s_ = (o) * 256 + tid; const int r_ = s_ >> 2; \
    const int q_ = (s_ & 3) ^ ((r_ >> 1) & 3); \
    gl2lds16(B + (size_t)(n0 + r_) * K + (kbase) + q_ * 8, \
             SM + (slot) * 8192 + 4096 + s_ * 8); } while (0)
#define DSA(slot, row) (*(const bf16x8*)(SM + (slot) * 8192 + (row) * 32 + ((q2 ^ (((row) >> 1) & 3)) << 3)))
#define DSB(slot, row) (*(const bf16x8*)(SM + (slot) * 8192 + 4096 + (row) * 32 + ((q2 ^ (((row) >> 1) & 3)) << 3)))
#define BARQ() asm volatile("s_barrier" ::: "memory")

    f32x4 acc[4][4];
    const f32x4 z4 = {0.f, 0.f, 0.f, 0.f};
#pragma unroll
    for (int i = 0; i < 4; i++)
#pragma unroll
        for (int j = 0; j < 4; j++) acc[i][j] = z4;

    // prologue: chunks 0,1 staged (8 ops); drain c0 (vmcnt(4): c1 in flight)
    STG_A(0, 0, 0);  STG_A(0, 0, 1);  STG_B(0, 0, 0);  STG_B(0, 0, 1);
    STG_A(1, 32, 0); STG_A(1, 32, 1); STG_B(1, 32, 0); STG_B(1, 32, 1);
    asm volatile("s_waitcnt vmcnt(4)" ::: "memory");
    BARQ();

    int scur = 0;
    for (int c = 0; c < NC; ++c) {
        const int s2 = (scur >= 1) ? scur - 1 : scur + 2;   // (scur+2)%3
        if (c <= NC - 3) {
            const int kn = (c + 2) << 5;
            STG_A(s2, kn, 0); STG_A(s2, kn, 1); STG_B(s2, kn, 0); STG_B(s2, kn, 1);
        }
        bf16x8 a[4], b[4];
#pragma unroll
        for (int ii = 0; ii < 4; ii++) a[ii] = DSA(scur, wm * 64 + ii * 16 + ln);
#pragma unroll
        for (int jj = 0; jj < 4; jj++) b[jj] = DSB(scur, wn * 64 + jj * 16 + ln);
        __builtin_amdgcn_s_setprio(1);
#pragma unroll
        for (int ii = 0; ii < 4; ii++)
#pragma unroll
            for (int jj = 0; jj < 4; jj++)
                acc[ii][jj] = MFMA16(a[ii], b[jj], acc[ii][jj]);
        __builtin_amdgcn_s_setprio(0);
        if (c <= NC - 3)      { asm volatile("s_waitcnt vmcnt(4)" ::: "memory"); }
        else if (c == NC - 2) { asm volatile("s_waitcnt vmcnt(0)" ::: "memory"); }
        BARQ();
        scur = (scur == 2) ? 0 : scur + 1;
    }

    // epilogue: bias add, bf16 store (C layout: col = ln, row = q2*4 + r)
#pragma unroll
    for (int j = 0; j < 4; j++) {
        const int n = n0 + wn * 64 + j * 16 + ln;
        const float bv = bf2f(bias[n]);
#pragma unroll
        for (int i = 0; i < 4; i++) {
            const int mrow = m0 + wm * 64 + i * 16 + q2 * 4;
#pragma unroll
            for (int r = 0; r < 4; r++)
                C[(size_t)(mrow + r) * N + n] = f2bf(acc[i][j][r] + bv);
        }
    }
#undef STG_A
#undef STG_B
#undef DSA
#undef DSB
#undef BARQ
}

// ---------------------------------------------------------------------------
// Final GEMM: fp32 output when flag=1 (verified), bf16 otherwise. (m97-style)
// ---------------------------------------------------------------------------
__global__ __launch_bounds__(256) void gemm_bt_bias_out(
    const ushort_t* __restrict__ A, const ushort_t* __restrict__ B,
    const ushort_t* __restrict__ bias, void* __restrict__ C,
    int M, int N, int K, const int* __restrict__ flag)
{
    __shared__ __align__(16) ushort_t As[128 * 32];
    __shared__ __align__(16) ushort_t Bs[128 * 32];
    const int tid = threadIdx.x;
    const int w = tid >> 6, l = tid & 63, q = l >> 4, ln = l & 15;
    const int wm = w >> 1, wn = w & 1;
    const int m0 = blockIdx.y * 128, n0 = blockIdx.x * 128;
    const int sr = tid >> 2;
    const int sc = (tid & 3) * 8;

    f32x4 acc[4][4];
    const f32x4 z4 = {0.f, 0.f, 0.f, 0.f};
    for (int i = 0; i < 4; i++) for (int j = 0; j < 4; j++) acc[i][j] = z4;

    for (int k0 = 0; k0 < K; k0 += 32) {
        __syncthreads();
        gl2lds16(A + (size_t)(m0 + sr) * K + k0 + sc,       As + sr * 32 + sc);
        gl2lds16(A + (size_t)(m0 + 64 + sr) * K + k0 + sc,  As + (64 + sr) * 32 + sc);
        gl2lds16(B + (size_t)(n0 + sr) * K + k0 + sc,       Bs + sr * 32 + sc);
        gl2lds16(B + (size_t)(n0 + 64 + sr) * K + k0 + sc,  Bs + (64 + sr) * 32 + sc);
        __syncthreads();
        bf16x8 a[4], bb[4];
        for (int i = 0; i < 4; i++)
            a[i]  = *(const bf16x8*)(As + (wm * 64 + i * 16 + ln) * 32 + q * 8);
        for (int j = 0; j < 4; j++)
            bb[j] = *(const bf16x8*)(Bs + (wn * 64 + j * 16 + ln) * 32 + q * 8);
        for (int i = 0; i < 4; i++)
            for (int j = 0; j < 4; j++)
                acc[i][j] = MFMA16(a[i], bb[j], acc[i][j]);
    }
    const int f = flag[0];
    for (int j = 0; j < 4; j++) {
        const int n = n0 + wn * 64 + j * 16 + ln;
        const float bv = bf2f(bias[n]);
        for (int i = 0; i < 4; i++) {
            const int mrow = m0 + wm * 64 + i * 16 + q * 4;
            for (int r = 0; r < 4; r++) {
                const float val = acc[i][j][r] + bv;
                const size_t idx = (size_t)(mrow + r) * N + n;
                if (f) ((float*)C)[idx] = val;
                else   ((ushort_t*)C)[idx] = f2bf(val);
            }
        }
    }
}

// ---------------------------------------------------------------------------
// RoPE (unchanged, verified).
// ---------------------------------------------------------------------------
__global__ __launch_bounds__(256) void rope_kernel(ushort_t* qkv)
{
    const int bs = blockIdx.x;
    const int s = bs & 2047;
    const int t = threadIdx.x;
    const size_t base = (size_t)bs * 6144;
    float cv[8], sv[8], qa[8], qp[8], ka[8], kp[8];
    for (int u = 0; u < 8; u++) {
        const int e = u * 256 + t;
        const int j = e & 127;
        const int p = (j < 64) ? (2 * j + 1) : (2 * (j - 64));
        const int hb = e - j;
        const float ang = powf(10000.0f, -(float)(2 * (j >> 1)) / 2048.0f);
        sincosf((float)s * ang, &sv[u], &cv[u]);
        qa[u] = bf2f(qkv[base + hb + j]);
        qp[u] = bf2f(qkv[base + hb + p]);
        ka[u] = bf2f(qkv[base + 2048 + hb + j]);
        kp[u] = bf2f(qkv[base + 2048 + hb + p]);
    }
    __syncthreads();
    for (int u = 0; u < 8; u++) {
        const int e = u * 256 + t;
        const int j = e & 127;
        const int hb = e - j;
        const float sg = (j < 64) ? -1.0f : 1.0f;
        qkv[base + hb + j]        = f2bf(cv[u] * qa[u] + sv[u] * sg * qp[u]);
        qkv[base + 2048 + hb + j] = f2bf(cv[u] * ka[u] + sv[u] * sg * kp[u]);
    }
}

// ---------------------------------------------------------------------------
// Vt[b,h,d,s] = qkv[b,s,2,h,d] (unchanged, verified).
// ---------------------------------------------------------------------------
__global__ __launch_bounds__(256) void vtrans_kernel(const ushort_t* __restrict__ qkv,
                                                     ushort_t* __restrict__ Vt)
{
    __shared__ ushort_t tile[64][130];
    const int blk = blockIdx.x;
    const int st = blk & 31, h = (blk >> 5) & 15, b = blk >> 9;
    const int t = threadIdx.x;
    for (int i = 0; i < 32; i++) {
        const int e = i * 256 + t;
        const int r = e >> 7, c = e & 127;
        tile[r][c] = qkv[(size_t)(b * 2048 + st * 64 + r) * 6144 + 4096 + h * 128 + c];
    }
    __syncthreads();
    const int d = t >> 1, s0 = (t & 1) * 32;
    const size_t obase = ((size_t)(b * 16 + h) * 128 + d) * 2048 + st * 64 + s0;
    for (int k = 0; k < 32; k++)
        Vt[obase + k] = tile[s0 + k][d];
}

// ---------------------------------------------------------------------------
// Flash attention v3 (round-1, verified): swizzled Ks/Vs, T14 async-STAGE,
// T12 in-register P (cvt_pk + permlane32_swap), T13 defer-max, setprio.
// ---------------------------------------------------------------------------
__global__ __launch_bounds__(256, 2) void flash_kernel(
    const ushort_t* __restrict__ qkv, const ushort_t* __restrict__ Vt,
    const int* __restrict__ mask, ushort_t* __restrict__ AO)
{
    __shared__ __align__(16) ushort_t SM[16384];   // 32 KiB
    ushort_t* Ks = SM;          // [64][128] bf16, 16B-unit swizzle ^(row&15)
    ushort_t* Vs = SM + 8192;   // [128][64] bf16, 16B-unit swizzle ^(row&7)
    const int t = threadIdx.x;
    const int w = t >> 6, l = t & 63, lq = l & 31, q2 = l >> 5;
    const int qb = blockIdx.x * 128, h = blockIdx.y, b = blockIdx.z;
    const size_t brow = (size_t)b * 2048;
    const float scale = 0.08838834764831845f;   // 1/sqrt(128)
    const int qrow = qb + w * 32 + lq;
    const size_t vbase = (size_t)(b * 16 + h) * 128;

    bf16x8 qf[8];
#pragma unroll
    for (int kb = 0; kb < 8; kb++)
        qf[kb] = *(const bf16x8*)(qkv + (brow + qrow) * 6144 + h * 128 + kb * 16 + q2 * 8);

    float m_old = -1e30f, lsum = 0.f;
    f32x16 acc_o[4];
#pragma unroll
    for (int dt = 0; dt < 4; dt++)
#pragma unroll
        for (int r = 0; r < 16; r++) acc_o[dt][r] = 0.f;

    bf16x8 kst[4], vst[4];
#pragma unroll
    for (int i = 0; i < 4; i++) {
        const int s_ = i * 256 + t; const int row = s_ >> 4; const int u = s_ & 15;
        kst[i] = *(const bf16x8*)(qkv + (brow + row) * 6144 + 2048 + h * 128 + u * 8);
    }
#pragma unroll
    for (int i = 0; i < 4; i++) {
        const int s_ = i * 256 + t; const int row = s_ >> 3; const int u = s_ & 7;
        vst[i] = *(const bf16x8*)(Vt + (vbase + row) * 2048 + u * 8);
    }

    for (int s0 = 0; s0 < 2048; s0 += 64) {
        const int mk = mask[brow + s0 + l];
        const unsigned long long bm = __ballot(mk != 0);
        asm volatile("s_waitcnt lgkmcnt(0)" ::: "memory");
        asm volatile("s_barrier" ::: "memory");          // all waves done reading prev tile
#pragma unroll
        for (int i = 0; i < 4; i++) {
            const int s_ = i * 256 + t; const int row = s_ >> 4; const int u = s_ & 15;
            *(bf16x8*)(Ks + row * 128 + ((u ^ (row & 15)) << 3)) = kst[i];
        }
#pragma unroll
        for (int i = 0; i < 4; i++) {
            const int s_ = i * 256 + t; const int row = s_ >> 3; const int u = s_ & 7;
            *(bf16x8*)(Vs + row * 64 + ((u ^ (row & 7)) << 3)) = vst[i];
        }
        if (s0 + 64 < 2048) {
#pragma unroll
            for (int i = 0; i < 4; i++) {
                const int s_ = i * 256 + t; const int row = s_ >> 4; const int u = s_ & 15;
                kst[i] = *(const bf16x8*)(qkv + (brow + s0 + 64 + row) * 6144 + 2048 + h * 128 + u * 8);
            }
#pragma unroll
            for (int i = 0; i < 4; i++) {
                const int s_ = i * 256 + t; const int row = s_ >> 3; const int u = s_ & 7;
                vst[i] = *(const bf16x8*)(Vt + (vbase + row) * 2048 + s0 + 64 + u * 8);
            }
        }
        asm volatile("s_waitcnt lgkmcnt(0)" ::: "memory");  // ds_writes drained (NOT vmcnt)
        asm volatile("s_barrier" ::: "memory");             // writes visible

        f32x16 sa[2];
#pragma unroll
        for (int mt = 0; mt < 2; mt++) {
#pragma unroll
            for (int r = 0; r < 16; r++) sa[mt][r] = 0.f;
            const int row = mt * 32 + lq;
            __builtin_amdgcn_s_setprio(1);
#pragma unroll
            for (int kb = 0; kb < 8; kb++) {
                bf16x8 a = *(const bf16x8*)(Ks + row * 128 + (((kb * 2 + q2) ^ (row & 15)) << 3));
                sa[mt] = MFMA32(a, qf[kb], sa[mt]);
            }
            __builtin_amdgcn_s_setprio(0);
        }
        float p[32];
        float mr = -1e30f;
        if (bm == ~0ull) {
#pragma unroll
            for (int mt = 0; mt < 2; mt++)
#pragma unroll
                for (int r = 0; r < 16; r++) {
                    const float v = sa[mt][r] * scale;
                    p[mt * 16 + r] = v;
                    mr = fmaxf(mr, v);
                }
        } else {
#pragma unroll
            for (int mt = 0; mt < 2; mt++)
#pragma unroll
                for (int r = 0; r < 16; r++) {
                    const int srow = mt * 32 + (r & 3) + 8 * (r >> 2) + 4 * q2;
                    const float bias = ((bm >> srow) & 1ull) ? 0.f : -1e9f;
                    const float v = sa[mt][r] * scale + bias;
                    p[mt * 16 + r] = v;
                    mr = fmaxf(mr, v);
                }
        }
        mr = fmaxf(mr, __shfl_xor(mr, 32, 64));
        if (!__all(mr <= m_old + 8.0f)) {        // T13 defer-max
            const float mnew = fmaxf(m_old, mr);
            const float alpha = __expf(m_old - mnew);
            lsum *= alpha;
#pragma unroll
            for (int dt = 0; dt < 4; dt++)
#pragma unroll
                for (int r = 0; r < 16; r++) acc_o[dt][r] *= alpha;
            m_old = mnew;
        }
        float rs = 0.f;
#pragma unroll
        for (int i = 0; i < 32; i++) { p[i] = __expf(p[i] - m_old); rs += p[i]; }
        rs += __shfl_xor(rs, 32, 64);
        lsum += rs;

#pragma unroll
        for (int kb = 0; kb < 4; kb++) {
            const int bb = (kb >> 1) * 16 + (kb & 1) * 8;
            unsigned w01, w23, w45, w67;
            asm("v_cvt_pk_bf16_f32 %0, %1, %2" : "=v"(w01) : "v"(p[bb + 0]), "v"(p[bb + 1]));
            asm("v_cvt_pk_bf16_f32 %0, %1, %2" : "=v"(w23) : "v"(p[bb + 2]), "v"(p[bb + 3]));
            asm("v_cvt_pk_bf16_f32 %0, %1, %2" : "=v"(w45) : "v"(p[bb + 4]), "v"(p[bb + 5]));
            asm("v_cvt_pk_bf16_f32 %0, %1, %2" : "=v"(w67) : "v"(p[bb + 6]), "v"(p[bb + 7]));
            asm("v_permlane32_swap_b32 %0, %1" : "+v"(w01), "+v"(w45));
            asm("v_permlane32_swap_b32 %0, %1" : "+v"(w23), "+v"(w67));
            union { unsigned u[4]; bf16x8 v8; } pu;
            pu.u[0] = w01; pu.u[1] = w23; pu.u[2] = w45; pu.u[3] = w67;
            __builtin_amdgcn_s_setprio(1);
#pragma unroll
            for (int dt = 0; dt < 4; dt++) {
                const int row = dt * 32 + lq;
                bf16x8 va = *(const bf16x8*)(Vs + row * 64 + (((kb * 2 + q2) ^ (row & 7)) << 3));
                acc_o[dt] = MFMA32(va, pu.v8, acc_o[dt]);
            }
            __builtin_amdgcn_s_setprio(0);
        }
    }
    __syncthreads();   // all PV reads done before epilogue overlays SM
    const float inv = (lsum > 0.f) ? 1.0f / lsum : 0.f;
#pragma unroll
    for (int dt = 0; dt < 4; dt++)
#pragma unroll
        for (int r2 = 0; r2 < 4; r2++) {
            us4 ov;
#pragma unroll
            for (int j = 0; j < 4; j++) ov[j] = f2bf(acc_o[dt][r2 * 4 + j] * inv);
            const int row = w * 32 + lq;
            const int unit = dt * 4 + r2;
            *(us4*)(SM + row * 128 + ((unit ^ (row & 15)) << 3) + q2 * 4) = ov;
        }
    __syncthreads();
#pragma unroll
    for (int i = 0; i < 8; i++) {
        const int rl = i * 4 + (l >> 4), ch = l & 15;
        const int row = w * 32 + rl;
        bf16x8 vv = *(const bf16x8*)(SM + row * 128 + ((ch ^ (row & 15)) << 3));
        *(bf16x8*)(AO + (brow + qb + row) * 2048 + h * 128 + ch * 8) = vv;
    }
}

extern "C" void kernel_launch(void* const* d_in, const int* in_sizes, int n_in,
                              void* d_out, int out_size, void* d_ws, size_t ws_size,
                              hipStream_t stream)
{
    (void)in_sizes; (void)n_in; (void)out_size; (void)ws_size;
    const void* X    = d_in[0];
    const int*  mask = (const int*)d_in[1];
    const void* Wqkv = d_in[2];
    const void* bqkv = d_in[3];
    const void* Wo   = d_in[4];
    const void* bo   = d_in[5];

    int*      flag  = (int*)d_ws;
    ushort_t* Xc    = (ushort_t*)d_ws + 16;
    ushort_t* Wqkvc = Xc + 8388608;
    ushort_t* bqkvc = Wqkvc + 12582912;
    ushort_t* Woc   = bqkvc + 6144;
    ushort_t* boc   = Woc + 4194304;
    ushort_t* qkv   = boc + 2048;
    ushort_t* Vt    = Wqkvc;   // reuse: Wqkv dead after gemm1
    ushort_t* AO    = Xc;      // reuse: X dead after gemm1

    detect_kernel<<<1, 256, 0, stream>>>((const ushort_t*)Wqkv, flag);
    convert_kernel<<<4096, 256, 0, stream>>>(X,    Xc,    8388608,  flag);
    convert_kernel<<<6144, 256, 0, stream>>>(Wqkv, Wqkvc, 12582912, flag);
    convert_kernel<<<3,    256, 0, stream>>>(bqkv, bqkvc, 6144,     flag);
    convert_kernel<<<2048, 256, 0, stream>>>(Wo,   Woc,   4194304,  flag);
    convert_kernel<<<1,    256, 0, stream>>>(bo,   boc,   2048,     flag);

    gemm_qkv_bt_bias<<<dim3(6144 / 128, 4096 / 128), 256, 0, stream>>>(Xc, Wqkvc, bqkvc, qkv, 4096, 6144, 2048);
    rope_kernel<<<4096, 256, 0, stream>>>(qkv);
    vtrans_kernel<<<1024, 256, 0, stream>>>(qkv, Vt);
    flash_kernel<<<dim3(16, 16, 2), 256, 0, stream>>>(qkv, Vt, mask, AO);
    gemm_bt_bias_out<<<dim3(2048 / 128, 4096 / 128), 256, 0, stream>>>(AO, Woc, boc, d_out, 4096, 2048, 2048, flag);
}

// Round 6
// 607.758 us; speedup vs baseline: 1.0142x; 1.0142x over previous
//
#include <hip/hip_runtime.h>
#include <hip/hip_bf16.h>
#include <math.h>

typedef __bf16 bf16x8 __attribute__((ext_vector_type(8)));
typedef float  f32x4  __attribute__((ext_vector_type(4)));
typedef float  f32x16 __attribute__((ext_vector_type(16)));
typedef unsigned short ushort_t;
typedef ushort_t us4 __attribute__((ext_vector_type(4)));

#define MFMA16(a, b, c) __builtin_amdgcn_mfma_f32_16x16x32_bf16((a), (b), (c), 0, 0, 0)
#define MFMA32(a, b, c) __builtin_amdgcn_mfma_f32_32x32x16_bf16((a), (b), (c), 0, 0, 0)

__device__ __forceinline__ float bf2f(ushort_t h) {
    union { unsigned u; float f; } v; v.u = ((unsigned)h) << 16; return v.f;
}
__device__ __forceinline__ ushort_t f2bf(float x) {
    union { float f; unsigned u; } v; v.f = x;
    unsigned r = v.u + 0x7FFFu + ((v.u >> 16) & 1u);
    return (ushort_t)(r >> 16);
}
// async global->LDS, 16B per lane. LDS dest must be wave-uniform base + lane*16.
__device__ __forceinline__ void gl2lds16(const void* g, void* l) {
    __builtin_amdgcn_global_load_lds((__attribute__((address_space(1))) void*)(g),
                                     (__attribute__((address_space(3))) void*)(l),
                                     16, 0, 0);
}

// ---------------------------------------------------------------------------
// Dtype detector (verified: flag=1 fires, inputs are fp32).
// ---------------------------------------------------------------------------
__global__ __launch_bounds__(256) void detect_kernel(const ushort_t* __restrict__ w, int* flag)
{
    __shared__ int cnt[256];
    const int t = threadIdx.x;
    int c = 0;
    for (int i = t; i < 65536; i += 256) {
        const unsigned hw = w[i];
        const unsigned e = (hw >> 7) & 0xFFu;
        if (e == 0xFFu || (e == 0u && (hw & 0x7Fu) != 0u)) c++;
    }
    cnt[t] = c;
    __syncthreads();
    for (int s = 128; s > 0; s >>= 1) {
        if (t < s) cnt[t] += cnt[t + s];
        __syncthreads();
    }
    if (t == 0) flag[0] = (cnt[0] >= 8) ? 1 : 0;
}

__global__ __launch_bounds__(256) void convert_kernel(const void* __restrict__ src,
                                                      ushort_t* __restrict__ dst,
                                                      int n, const int* __restrict__ flag)
{
    const int i0 = (blockIdx.x * 256 + threadIdx.x) * 8;
    if (i0 + 8 > n) return;
    if (flag[0]) {
        const f32x4 a = *(const f32x4*)((const float*)src + i0);
        const f32x4 b = *(const f32x4*)((const float*)src + i0 + 4);
        ushort_t o[8];
        o[0]=f2bf(a[0]); o[1]=f2bf(a[1]); o[2]=f2bf(a[2]); o[3]=f2bf(a[3]);
        o[4]=f2bf(b[0]); o[5]=f2bf(b[1]); o[6]=f2bf(b[2]); o[7]=f2bf(b[3]);
        *(bf16x8*)(dst + i0) = *(const bf16x8*)o;
    } else {
        *(bf16x8*)(dst + i0) = *(const bf16x8*)((const ushort_t*)src + i0);
    }
}

// ---------------------------------------------------------------------------
// 256x256-tile 8-phase GEMM, C = A * B^T + bias (bf16 in/out).
// ROUND-5: REVERTED VERBATIM to the round-0 kernel (measured 145us, best of
// rounds 0-4; rounds 2/3/4 restructures were neutral or regressed).
// ---------------------------------------------------------------------------
__global__ __launch_bounds__(512, 2) void gemm256_bt_bias(
    const ushort_t* __restrict__ A, const ushort_t* __restrict__ B,
    const ushort_t* __restrict__ bias, ushort_t* __restrict__ C,
    int M, int N, int K)
{
    __shared__ __align__(16) ushort_t SM[65536];   // 4 slots x (8192 A + 8192 B) ushorts
    const int tid = threadIdx.x;
    const int l = tid & 63, ln = l & 15, q2 = l >> 4;
    const int w = tid >> 6, wm = w >> 2, wn = w & 3;
    const int m0 = blockIdx.y * 256, n0 = blockIdx.x * 256;
    const int NT = K >> 6;

#define STG_A256(slot, kbase, o) do { \
    const int s_ = (o) * 512 + tid; const int r_ = s_ >> 2; \
    const int q_ = (s_ & 3) ^ ((r_ >> 1) & 3); \
    gl2lds16(A + (size_t)(m0 + r_) * K + (kbase) + q_ * 8, \
             SM + (slot) * 16384 + s_ * 8); } while (0)
#define STG_B256(slot, kbase, o) do { \
    const int s_ = (o) * 512 + tid; const int r_ = s_ >> 2; \
    const int q_ = (s_ & 3) ^ ((r_ >> 1) & 3); \
    gl2lds16(B + (size_t)(n0 + r_) * K + (kbase) + q_ * 8, \
             SM + (slot) * 16384 + 8192 + s_ * 8); } while (0)
#define DSA256(slot, row) (*(const bf16x8*)(SM + (slot) * 16384 + (row) * 32 + ((q2 ^ (((row) >> 1) & 3)) << 3)))
#define DSB256(slot, row) (*(const bf16x8*)(SM + (slot) * 16384 + 8192 + (row) * 32 + ((q2 ^ (((row) >> 1) & 3)) << 3)))
#define BAR256() asm volatile("s_barrier" ::: "memory")

    f32x4 acc[8][4];
    const f32x4 z4 = {0.f, 0.f, 0.f, 0.f};
#pragma unroll
    for (int i = 0; i < 8; i++)
#pragma unroll
        for (int j = 0; j < 4; j++) acc[i][j] = z4;

    STG_A256(0, 0, 0);  STG_A256(0, 0, 1);  STG_B256(0, 0, 0);  STG_B256(0, 0, 1);
    STG_A256(1, 32, 0); STG_A256(1, 32, 1); STG_B256(1, 32, 0); STG_B256(1, 32, 1);
    if (NT > 1) STG_A256(2, 64, 0);
    asm volatile("s_waitcnt vmcnt(5)" ::: "memory");
    BAR256();

    for (int t = 0; t < NT; ++t) {
        const int s0 = (2 * t) & 3, s1 = (2 * t + 1) & 3;
        const int sA = (2 * t + 2) & 3, sB = (2 * t + 3) & 3;
        const int kA = (t + 1) << 6, kB = kA + 32, kC = (t + 2) << 6;
        const bool stAB = (t < NT - 1), stC = (t < NT - 2);
        const int rA0 = wm * 128, rA1 = wm * 128 + 64, rB = wn * 64;
        bf16x8 a0[4], a1[4], b00[2], b01[2], b10[2], b11[2];

        // ---- p0
#pragma unroll
        for (int ii = 0; ii < 4; ii++) a0[ii] = DSA256(s0, rA0 + ii * 16 + ln);
        b00[0] = DSB256(s0, rB + ln);
        b00[1] = DSB256(s0, rB + 16 + ln);
        if (stAB) STG_A256(sA, kA, 1);
        __builtin_amdgcn_s_setprio(1);
#pragma unroll
        for (int ii = 0; ii < 4; ii++) {
            acc[ii][0] = MFMA16(a0[ii], b00[0], acc[ii][0]);
            acc[ii][1] = MFMA16(a0[ii], b00[1], acc[ii][1]);
        }
        __builtin_amdgcn_s_setprio(0);
        if (stAB) { asm volatile("s_waitcnt vmcnt(2)" ::: "memory"); }
        else      { asm volatile("s_waitcnt vmcnt(0)" ::: "memory"); }
        BAR256();

        // ---- p1
#pragma unroll
        for (int ii = 0; ii < 4; ii++) a1[ii] = DSA256(s1, rA0 + ii * 16 + ln);
        b01[0] = DSB256(s1, rB + ln);
        b01[1] = DSB256(s1, rB + 16 + ln);
        if (stAB) STG_B256(sA, kA, 0);
        __builtin_amdgcn_s_setprio(1);
#pragma unroll
        for (int ii = 0; ii < 4; ii++) {
            acc[ii][0] = MFMA16(a1[ii], b01[0], acc[ii][0]);
            acc[ii][1] = MFMA16(a1[ii], b01[1], acc[ii][1]);
        }
        __builtin_amdgcn_s_setprio(0);
        BAR256();

        // ---- p2
        b10[0] = DSB256(s0, rB + 32 + ln);
        b10[1] = DSB256(s0, rB + 48 + ln);
        if (stAB) STG_B256(sA, kA, 1);
        __builtin_amdgcn_s_setprio(1);
#pragma unroll
        for (int ii = 0; ii < 4; ii++) {
            acc[ii][2] = MFMA16(a0[ii], b10[0], acc[ii][2]);
            acc[ii][3] = MFMA16(a0[ii], b10[1], acc[ii][3]);
        }
        __builtin_amdgcn_s_setprio(0);
        BAR256();

        // ---- p3
        b11[0] = DSB256(s1, rB + 32 + ln);
        b11[1] = DSB256(s1, rB + 48 + ln);
        if (stAB) STG_A256(sB, kB, 0);
        __builtin_amdgcn_s_setprio(1);
#pragma unroll
        for (int ii = 0; ii < 4; ii++) {
            acc[ii][2] = MFMA16(a1[ii], b11[0], acc[ii][2]);
            acc[ii][3] = MFMA16(a1[ii], b11[1], acc[ii][3]);
        }
        __builtin_amdgcn_s_setprio(0);
        BAR256();

        // ---- p4
#pragma unroll
        for (int ii = 0; ii < 4; ii++) a0[ii] = DSA256(s0, rA1 + ii * 16 + ln);
        if (stAB) STG_A256(sB, kB, 1);
        __builtin_amdgcn_s_setprio(1);
#pragma unroll
        for (int ii = 0; ii < 4; ii++) {
            acc[4 + ii][2] = MFMA16(a0[ii], b10[0], acc[4 + ii][2]);
            acc[4 + ii][3] = MFMA16(a0[ii], b10[1], acc[4 + ii][3]);
        }
        __builtin_amdgcn_s_setprio(0);
        BAR256();

        // ---- p5
#pragma unroll
        for (int ii = 0; ii < 4; ii++) a1[ii] = DSA256(s1, rA1 + ii * 16 + ln);
        if (stAB) STG_B256(sB, kB, 0);
        __builtin_amdgcn_s_setprio(1);
#pragma unroll
        for (int ii = 0; ii < 4; ii++) {
            acc[4 + ii][2] = MFMA16(a1[ii], b11[0], acc[4 + ii][2]);
            acc[4 + ii][3] = MFMA16(a1[ii], b11[1], acc[4 + ii][3]);
        }
        __builtin_amdgcn_s_setprio(0);
        BAR256();

        // ---- p6
        if (stAB) STG_B256(sB, kB, 1);
        __builtin_amdgcn_s_setprio(1);
#pragma unroll
        for (int ii = 0; ii < 4; ii++) {
            acc[4 + ii][0] = MFMA16(a0[ii], b00[0], acc[4 + ii][0]);
            acc[4 + ii][1] = MFMA16(a0[ii], b00[1], acc[4 + ii][1]);
        }
        __builtin_amdgcn_s_setprio(0);
        BAR256();

        // ---- p7
        if (stC) STG_A256(s0, kC, 0);
        __builtin_amdgcn_s_setprio(1);
#pragma unroll
        for (int ii = 0; ii < 4; ii++) {
            acc[4 + ii][0] = MFMA16(a1[ii], b01[0], acc[4 + ii][0]);
            acc[4 + ii][1] = MFMA16(a1[ii], b01[1], acc[4 + ii][1]);
        }
        __builtin_amdgcn_s_setprio(0);
        if (t < NT - 2)       { asm volatile("s_waitcnt vmcnt(5)" ::: "memory"); }
        else if (t == NT - 2) { asm volatile("s_waitcnt vmcnt(4)" ::: "memory"); }
        BAR256();
    }

#pragma unroll
    for (int j = 0; j < 4; j++) {
        const int n = n0 + wn * 64 + j * 16 + ln;
        const float bv = bf2f(bias[n]);
#pragma unroll
        for (int i = 0; i < 8; i++) {
            const int mrow = m0 + wm * 128 + i * 16 + q2 * 4;
#pragma unroll
            for (int r = 0; r < 4; r++)
                C[(size_t)(mrow + r) * N + n] = f2bf(acc[i][j][r] + bv);
        }
    }
#undef STG_A256
#undef STG_B256
#undef DSA256
#undef DSB256
#undef BAR256
}

// ---------------------------------------------------------------------------
// Final GEMM: fp32 output when flag=1 (verified), bf16 otherwise. (m97-style)
// ---------------------------------------------------------------------------
__global__ __launch_bounds__(256) void gemm_bt_bias_out(
    const ushort_t* __restrict__ A, const ushort_t* __restrict__ B,
    const ushort_t* __restrict__ bias, void* __restrict__ C,
    int M, int N, int K, const int* __restrict__ flag)
{
    __shared__ __align__(16) ushort_t As[128 * 32];
    __shared__ __align__(16) ushort_t Bs[128 * 32];
    const int tid = threadIdx.x;
    const int w = tid >> 6, l = tid & 63, q = l >> 4, ln = l & 15;
    const int wm = w >> 1, wn = w & 1;
    const int m0 = blockIdx.y * 128, n0 = blockIdx.x * 128;
    const int sr = tid >> 2;
    const int sc = (tid & 3) * 8;

    f32x4 acc[4][4];
    const f32x4 z4 = {0.f, 0.f, 0.f, 0.f};
    for (int i = 0; i < 4; i++) for (int j = 0; j < 4; j++) acc[i][j] = z4;

    for (int k0 = 0; k0 < K; k0 += 32) {
        __syncthreads();
        gl2lds16(A + (size_t)(m0 + sr) * K + k0 + sc,       As + sr * 32 + sc);
        gl2lds16(A + (size_t)(m0 + 64 + sr) * K + k0 + sc,  As + (64 + sr) * 32 + sc);
        gl2lds16(B + (size_t)(n0 + sr) * K + k0 + sc,       Bs + sr * 32 + sc);
        gl2lds16(B + (size_t)(n0 + 64 + sr) * K + k0 + sc,  Bs + (64 + sr) * 32 + sc);
        __syncthreads();
        bf16x8 a[4], bb[4];
        for (int i = 0; i < 4; i++)
            a[i]  = *(const bf16x8*)(As + (wm * 64 + i * 16 + ln) * 32 + q * 8);
        for (int j = 0; j < 4; j++)
            bb[j] = *(const bf16x8*)(Bs + (wn * 64 + j * 16 + ln) * 32 + q * 8);
        for (int i = 0; i < 4; i++)
            for (int j = 0; j < 4; j++)
                acc[i][j] = MFMA16(a[i], bb[j], acc[i][j]);
    }
    const int f = flag[0];
    for (int j = 0; j < 4; j++) {
        const int n = n0 + wn * 64 + j * 16 + ln;
        const float bv = bf2f(bias[n]);
        for (int i = 0; i < 4; i++) {
            const int mrow = m0 + wm * 64 + i * 16 + q * 4;
            for (int r = 0; r < 4; r++) {
                const float val = acc[i][j][r] + bv;
                const size_t idx = (size_t)(mrow + r) * N + n;
                if (f) ((float*)C)[idx] = val;
                else   ((ushort_t*)C)[idx] = f2bf(val);
            }
        }
    }
}

// ---------------------------------------------------------------------------
// RoPE — ROUND-5 vectorized rewrite. Thread (head h, octet i) owns outputs
// j in [8i,8i+8) and [64+8i,64+8i+8) of one head-row:
//   out[j]    = c(j)*x[j]    - s(j)*x[2j+1]        (j<64)
//   out[64+k] = c(64+k)*x[64+k] + s(64+k)*x[2k]
// partners 2j+1 / 2k for j,k in [8i,8i+8) all lie in x[16i..16i+16) -> four
// bf16x8 loads (L0=x[8i..], L1=x[64+8i..], L2=x[16i..], L3=x[16i+8..]) cover
// self+partner; two bf16x8 stores. ang(j) = 10000^(-(2*(j>>1))/2048), same as
// the verified scalar version. threads 0-127 = Q, 128-255 = K of one (b,s) row.
// Load-all -> __syncthreads -> store-all preserves the cross-thread RAW hazard
// discipline (partner region [16i,16i+16) is written by threads 2i,2i+1).
// ---------------------------------------------------------------------------
__global__ __launch_bounds__(256) void rope_kernel(ushort_t* qkv)
{
    const int bs = blockIdx.x;
    const int s = bs & 2047;
    const int t = threadIdx.x;
    const int qk = t >> 7;              // 0 = Q, 1 = K
    const int u = t & 127;
    const int h = u >> 3, i = u & 7;
    ushort_t* row = qkv + (size_t)bs * 6144 + qk * 2048 + h * 128;

    union { bf16x8 v; ushort_t e[8]; } L0, L1, L2, L3;
    L0.v = *(const bf16x8*)(row + 8 * i);
    L1.v = *(const bf16x8*)(row + 64 + 8 * i);
    L2.v = *(const bf16x8*)(row + 16 * i);
    L3.v = *(const bf16x8*)(row + 16 * i + 8);

    float ca[4], sa_[4], cb[4], sb[4];
#pragma unroll
    for (int e = 0; e < 4; e++) {
        const float angA = powf(10000.0f, -(float)(2 * (4 * i + e)) / 2048.0f);
        const float angB = powf(10000.0f, -(float)(2 * (32 + 4 * i + e)) / 2048.0f);
        sincosf((float)s * angA, &sa_[e], &ca[e]);
        sincosf((float)s * angB, &sb[e], &cb[e]);
    }
    __syncthreads();
    ushort_t oA[8], oB[8];
#pragma unroll
    for (int d = 0; d < 8; d++) {
        const int e = d >> 1;
        const float pA = (d < 4) ? bf2f(L2.e[2 * d + 1]) : bf2f(L3.e[2 * d - 7]);
        const float pB = (d < 4) ? bf2f(L2.e[2 * d])     : bf2f(L3.e[2 * d - 8]);
        oA[d] = f2bf(ca[e] * bf2f(L0.e[d]) - sa_[e] * pA);
        oB[d] = f2bf(cb[e] * bf2f(L1.e[d]) + sb[e] * pB);
    }
    *(bf16x8*)(row + 8 * i)      = *(const bf16x8*)oA;
    *(bf16x8*)(row + 64 + 8 * i) = *(const bf16x8*)oB;
}

// ---------------------------------------------------------------------------
// Vt[b,h,d,s] = qkv[b,s,2,h,d] — ROUND-5: vectorized loads (bf16x8, was 2B
// scalar) + vectorized stores (4x bf16x8/thread). Pitch 130 -> 136 keeps rows
// 16B-aligned for b128 LDS ops. Same (r,c)->(d,s) mapping as verified version.
// ---------------------------------------------------------------------------
__global__ __launch_bounds__(256) void vtrans_kernel(const ushort_t* __restrict__ qkv,
                                                     ushort_t* __restrict__ Vt)
{
    __shared__ __align__(16) ushort_t tile[64][136];
    const int blk = blockIdx.x;
    const int st = blk & 31, h = (blk >> 5) & 15, b = blk >> 9;
    const int t = threadIdx.x;
#pragma unroll
    for (int i = 0; i < 4; i++) {
        const int e = i * 256 + t;
        const int r = e >> 4, cb = e & 15;
        *(bf16x8*)(&tile[r][cb * 8]) =
            *(const bf16x8*)(qkv + (size_t)(b * 2048 + st * 64 + r) * 6144 + 4096 + h * 128 + cb * 8);
    }
    __syncthreads();
    const int d = t >> 1, s0 = (t & 1) * 32;
    const size_t obase = ((size_t)(b * 16 + h) * 128 + d) * 2048 + st * 64 + s0;
#pragma unroll
    for (int q4 = 0; q4 < 4; q4++) {
        ushort_t tmp[8];
#pragma unroll
        for (int j = 0; j < 8; j++) tmp[j] = tile[s0 + q4 * 8 + j][d];
        *(bf16x8*)(Vt + obase + q4 * 8) = *(const bf16x8*)tmp;
    }
}

// ---------------------------------------------------------------------------
// Flash attention v3 (round-1, verified): swizzled Ks/Vs, T14 async-STAGE,
// T12 in-register P (cvt_pk + permlane32_swap), T13 defer-max, setprio.
// ---------------------------------------------------------------------------
__global__ __launch_bounds__(256, 2) void flash_kernel(
    const ushort_t* __restrict__ qkv, const ushort_t* __restrict__ Vt,
    const int* __restrict__ mask, ushort_t* __restrict__ AO)
{
    __shared__ __align__(16) ushort_t SM[16384];   // 32 KiB
    ushort_t* Ks = SM;          // [64][128] bf16, 16B-unit swizzle ^(row&15)
    ushort_t* Vs = SM + 8192;   // [128][64] bf16, 16B-unit swizzle ^(row&7)
    const int t = threadIdx.x;
    const int w = t >> 6, l = t & 63, lq = l & 31, q2 = l >> 5;
    const int qb = blockIdx.x * 128, h = blockIdx.y, b = blockIdx.z;
    const size_t brow = (size_t)b * 2048;
    const float scale = 0.08838834764831845f;   // 1/sqrt(128)
    const int qrow = qb + w * 32 + lq;
    const size_t vbase = (size_t)(b * 16 + h) * 128;

    bf16x8 qf[8];
#pragma unroll
    for (int kb = 0; kb < 8; kb++)
        qf[kb] = *(const bf16x8*)(qkv + (brow + qrow) * 6144 + h * 128 + kb * 16 + q2 * 8);

    float m_old = -1e30f, lsum = 0.f;
    f32x16 acc_o[4];
#pragma unroll
    for (int dt = 0; dt < 4; dt++)
#pragma unroll
        for (int r = 0; r < 16; r++) acc_o[dt][r] = 0.f;

    bf16x8 kst[4], vst[4];
#pragma unroll
    for (int i = 0; i < 4; i++) {
        const int s_ = i * 256 + t; const int row = s_ >> 4; const int u = s_ & 15;
        kst[i] = *(const bf16x8*)(qkv + (brow + row) * 6144 + 2048 + h * 128 + u * 8);
    }
#pragma unroll
    for (int i = 0; i < 4; i++) {
        const int s_ = i * 256 + t; const int row = s_ >> 3; const int u = s_ & 7;
        vst[i] = *(const bf16x8*)(Vt + (vbase + row) * 2048 + u * 8);
    }

    for (int s0 = 0; s0 < 2048; s0 += 64) {
        const int mk = mask[brow + s0 + l];
        const unsigned long long bm = __ballot(mk != 0);
        asm volatile("s_waitcnt lgkmcnt(0)" ::: "memory");
        asm volatile("s_barrier" ::: "memory");          // all waves done reading prev tile
#pragma unroll
        for (int i = 0; i < 4; i++) {
            const int s_ = i * 256 + t; const int row = s_ >> 4; const int u = s_ & 15;
            *(bf16x8*)(Ks + row * 128 + ((u ^ (row & 15)) << 3)) = kst[i];
        }
#pragma unroll
        for (int i = 0; i < 4; i++) {
            const int s_ = i * 256 + t; const int row = s_ >> 3; const int u = s_ & 7;
            *(bf16x8*)(Vs + row * 64 + ((u ^ (row & 7)) << 3)) = vst[i];
        }
        if (s0 + 64 < 2048) {
#pragma unroll
            for (int i = 0; i < 4; i++) {
                const int s_ = i * 256 + t; const int row = s_ >> 4; const int u = s_ & 15;
                kst[i] = *(const bf16x8*)(qkv + (brow + s0 + 64 + row) * 6144 + 2048 + h * 128 + u * 8);
            }
#pragma unroll
            for (int i = 0; i < 4; i++) {
                const int s_ = i * 256 + t; const int row = s_ >> 3; const int u = s_ & 7;
                vst[i] = *(const bf16x8*)(Vt + (vbase + row) * 2048 + s0 + 64 + u * 8);
            }
        }
        asm volatile("s_waitcnt lgkmcnt(0)" ::: "memory");  // ds_writes drained (NOT vmcnt)
        asm volatile("s_barrier" ::: "memory");             // writes visible

        f32x16 sa[2];
#pragma unroll
        for (int mt = 0; mt < 2; mt++) {
#pragma unroll
            for (int r = 0; r < 16; r++) sa[mt][r] = 0.f;
            const int row = mt * 32 + lq;
            __builtin_amdgcn_s_setprio(1);
#pragma unroll
            for (int kb = 0; kb < 8; kb++) {
                bf16x8 a = *(const bf16x8*)(Ks + row * 128 + (((kb * 2 + q2) ^ (row & 15)) << 3));
                sa[mt] = MFMA32(a, qf[kb], sa[mt]);
            }
            __builtin_amdgcn_s_setprio(0);
        }
        float p[32];
        float mr = -1e30f;
        if (bm == ~0ull) {
#pragma unroll
            for (int mt = 0; mt < 2; mt++)
#pragma unroll
                for (int r = 0; r < 16; r++) {
                    const float v = sa[mt][r] * scale;
                    p[mt * 16 + r] = v;
                    mr = fmaxf(mr, v);
                }
        } else {
#pragma unroll
            for (int mt = 0; mt < 2; mt++)
#pragma unroll
                for (int r = 0; r < 16; r++) {
                    const int srow = mt * 32 + (r & 3) + 8 * (r >> 2) + 4 * q2;
                    const float bias = ((bm >> srow) & 1ull) ? 0.f : -1e9f;
                    const float v = sa[mt][r] * scale + bias;
                    p[mt * 16 + r] = v;
                    mr = fmaxf(mr, v);
                }
        }
        mr = fmaxf(mr, __shfl_xor(mr, 32, 64));
        if (!__all(mr <= m_old + 8.0f)) {        // T13 defer-max
            const float mnew = fmaxf(m_old, mr);
            const float alpha = __expf(m_old - mnew);
            lsum *= alpha;
#pragma unroll
            for (int dt = 0; dt < 4; dt++)
#pragma unroll
                for (int r = 0; r < 16; r++) acc_o[dt][r] *= alpha;
            m_old = mnew;
        }
        float rs = 0.f;
#pragma unroll
        for (int i = 0; i < 32; i++) { p[i] = __expf(p[i] - m_old); rs += p[i]; }
        rs += __shfl_xor(rs, 32, 64);
        lsum += rs;

#pragma unroll
        for (int kb = 0; kb < 4; kb++) {
            const int bb = (kb >> 1) * 16 + (kb & 1) * 8;
            unsigned w01, w23, w45, w67;
            asm("v_cvt_pk_bf16_f32 %0, %1, %2" : "=v"(w01) : "v"(p[bb + 0]), "v"(p[bb + 1]));
            asm("v_cvt_pk_bf16_f32 %0, %1, %2" : "=v"(w23) : "v"(p[bb + 2]), "v"(p[bb + 3]));
            asm("v_cvt_pk_bf16_f32 %0, %1, %2" : "=v"(w45) : "v"(p[bb + 4]), "v"(p[bb + 5]));
            asm("v_cvt_pk_bf16_f32 %0, %1, %2" : "=v"(w67) : "v"(p[bb + 6]), "v"(p[bb + 7]));
            asm("v_permlane32_swap_b32 %0, %1" : "+v"(w01), "+v"(w45));
            asm("v_permlane32_swap_b32 %0, %1" : "+v"(w23), "+v"(w67));
            union { unsigned u[4]; bf16x8 v8; } pu;
            pu.u[0] = w01; pu.u[1] = w23; pu.u[2] = w45; pu.u[3] = w67;
            __builtin_amdgcn_s_setprio(1);
#pragma unroll
            for (int dt = 0; dt < 4; dt++) {
                const int row = dt * 32 + lq;
                bf16x8 va = *(const bf16x8*)(Vs + row * 64 + (((kb * 2 + q2) ^ (row & 7)) << 3));
                acc_o[dt] = MFMA32(va, pu.v8, acc_o[dt]);
            }
            __builtin_amdgcn_s_setprio(0);
        }
    }
    __syncthreads();   // all PV reads done before epilogue overlays SM
    const float inv = (lsum > 0.f) ? 1.0f / lsum : 0.f;
#pragma unroll
    for (int dt = 0; dt < 4; dt++)
#pragma unroll
        for (int r2 = 0; r2 < 4; r2++) {
            us4 ov;
#pragma unroll
            for (int j = 0; j < 4; j++) ov[j] = f2bf(acc_o[dt][r2 * 4 + j] * inv);
            const int row = w * 32 + lq;
            const int unit = dt * 4 + r2;
            *(us4*)(SM + row * 128 + ((unit ^ (row & 15)) << 3) + q2 * 4) = ov;
        }
    __syncthreads();
#pragma unroll
    for (int i = 0; i < 8; i++) {
        const int rl = i * 4 + (l >> 4), ch = l & 15;
        const int row = w * 32 + rl;
        bf16x8 vv = *(const bf16x8*)(SM + row * 128 + ((ch ^ (row & 15)) << 3));
        *(bf16x8*)(AO + (brow + qb + row) * 2048 + h * 128 + ch * 8) = vv;
    }
}

extern "C" void kernel_launch(void* const* d_in, const int* in_sizes, int n_in,
                              void* d_out, int out_size, void* d_ws, size_t ws_size,
                              hipStream_t stream)
{
    (void)in_sizes; (void)n_in; (void)out_size; (void)ws_size;
    const void* X    = d_in[0];
    const int*  mask = (const int*)d_in[1];
    const void* Wqkv = d_in[2];
    const void* bqkv = d_in[3];
    const void* Wo   = d_in[4];
    const void* bo   = d_in[5];

    int*      flag  = (int*)d_ws;
    ushort_t* Xc    = (ushort_t*)d_ws + 16;
    ushort_t* Wqkvc = Xc + 8388608;
    ushort_t* bqkvc = Wqkvc + 12582912;
    ushort_t* Woc   = bqkvc + 6144;
    ushort_t* boc   = Woc + 4194304;
    ushort_t* qkv   = boc + 2048;
    ushort_t* Vt    = Wqkvc;   // reuse: Wqkv dead after gemm1
    ushort_t* AO    = Xc;      // reuse: X dead after gemm1

    detect_kernel<<<1, 256, 0, stream>>>((const ushort_t*)Wqkv, flag);
    convert_kernel<<<4096, 256, 0, stream>>>(X,    Xc,    8388608,  flag);
    convert_kernel<<<6144, 256, 0, stream>>>(Wqkv, Wqkvc, 12582912, flag);
    convert_kernel<<<3,    256, 0, stream>>>(bqkv, bqkvc, 6144,     flag);
    convert_kernel<<<2048, 256, 0, stream>>>(Wo,   Woc,   4194304,  flag);
    convert_kernel<<<1,    256, 0, stream>>>(bo,   boc,   2048,     flag);

    gemm256_bt_bias<<<dim3(6144 / 256, 4096 / 256), 512, 0, stream>>>(Xc, Wqkvc, bqkvc, qkv, 4096, 6144, 2048);
    rope_kernel<<<4096, 256, 0, stream>>>(qkv);
    vtrans_kernel<<<1024, 256, 0, stream>>>(qkv, Vt);
    flash_kernel<<<dim3(16, 16, 2), 256, 0, stream>>>(qkv, Vt, mask, AO);
    gemm_bt_bias_out<<<dim3(2048 / 128, 4096 / 128), 256, 0, stream>>>(AO, Woc, boc, d_out, 4096, 2048, 2048, flag);
}

// Round 7
// 548.966 us; speedup vs baseline: 1.1228x; 1.1071x over previous
//
#include <hip/hip_runtime.h>
#include <hip/hip_bf16.h>
#include <math.h>

typedef __bf16 bf16x8 __attribute__((ext_vector_type(8)));
typedef float  f32x4  __attribute__((ext_vector_type(4)));
typedef float  f32x16 __attribute__((ext_vector_type(16)));
typedef unsigned short ushort_t;
typedef ushort_t us4 __attribute__((ext_vector_type(4)));

#define MFMA16(a, b, c) __builtin_amdgcn_mfma_f32_16x16x32_bf16((a), (b), (c), 0, 0, 0)
#define MFMA32(a, b, c) __builtin_amdgcn_mfma_f32_32x32x16_bf16((a), (b), (c), 0, 0, 0)

__device__ __forceinline__ float bf2f(ushort_t h) {
    union { unsigned u; float f; } v; v.u = ((unsigned)h) << 16; return v.f;
}
__device__ __forceinline__ ushort_t f2bf(float x) {
    union { float f; unsigned u; } v; v.f = x;
    unsigned r = v.u + 0x7FFFu + ((v.u >> 16) & 1u);
    return (ushort_t)(r >> 16);
}
// async global->LDS, 16B per lane. LDS dest must be wave-uniform base + lane*16.
__device__ __forceinline__ void gl2lds16(const void* g, void* l) {
    __builtin_amdgcn_global_load_lds((__attribute__((address_space(1))) void*)(g),
                                     (__attribute__((address_space(3))) void*)(l),
                                     16, 0, 0);
}

// ---------------------------------------------------------------------------
// Dtype detector (verified: flag=1 fires, inputs are fp32).
// ---------------------------------------------------------------------------
__global__ __launch_bounds__(256) void detect_kernel(const ushort_t* __restrict__ w, int* flag)
{
    __shared__ int cnt[256];
    const int t = threadIdx.x;
    int c = 0;
    for (int i = t; i < 65536; i += 256) {
        const unsigned hw = w[i];
        const unsigned e = (hw >> 7) & 0xFFu;
        if (e == 0xFFu || (e == 0u && (hw & 0x7Fu) != 0u)) c++;
    }
    cnt[t] = c;
    __syncthreads();
    for (int s = 128; s > 0; s >>= 1) {
        if (t < s) cnt[t] += cnt[t + s];
        __syncthreads();
    }
    if (t == 0) flag[0] = (cnt[0] >= 8) ? 1 : 0;
}

__global__ __launch_bounds__(256) void convert_kernel(const void* __restrict__ src,
                                                      ushort_t* __restrict__ dst,
                                                      int n, const int* __restrict__ flag)
{
    const int i0 = (blockIdx.x * 256 + threadIdx.x) * 8;
    if (i0 + 8 > n) return;
    if (flag[0]) {
        const f32x4 a = *(const f32x4*)((const float*)src + i0);
        const f32x4 b = *(const f32x4*)((const float*)src + i0 + 4);
        ushort_t o[8];
        o[0]=f2bf(a[0]); o[1]=f2bf(a[1]); o[2]=f2bf(a[2]); o[3]=f2bf(a[3]);
        o[4]=f2bf(b[0]); o[5]=f2bf(b[1]); o[6]=f2bf(b[2]); o[7]=f2bf(b[3]);
        *(bf16x8*)(dst + i0) = *(const bf16x8*)o;
    } else {
        *(bf16x8*)(dst + i0) = *(const bf16x8*)((const ushort_t*)src + i0);
    }
}

// ---------------------------------------------------------------------------
// 256x256-tile 8-phase GEMM, C = A * B^T + bias (bf16 in/out).
// Round-0 kernel, kept verbatim (session best; rounds 2/3/4 restructures were
// neutral or regressed; session-to-session noise on this kernel is ~8%).
// ---------------------------------------------------------------------------
__global__ __launch_bounds__(512, 2) void gemm256_bt_bias(
    const ushort_t* __restrict__ A, const ushort_t* __restrict__ B,
    const ushort_t* __restrict__ bias, ushort_t* __restrict__ C,
    int M, int N, int K)
{
    __shared__ __align__(16) ushort_t SM[65536];   // 4 slots x (8192 A + 8192 B) ushorts
    const int tid = threadIdx.x;
    const int l = tid & 63, ln = l & 15, q2 = l >> 4;
    const int w = tid >> 6, wm = w >> 2, wn = w & 3;
    const int m0 = blockIdx.y * 256, n0 = blockIdx.x * 256;
    const int NT = K >> 6;

#define STG_A256(slot, kbase, o) do { \
    const int s_ = (o) * 512 + tid; const int r_ = s_ >> 2; \
    const int q_ = (s_ & 3) ^ ((r_ >> 1) & 3); \
    gl2lds16(A + (size_t)(m0 + r_) * K + (kbase) + q_ * 8, \
             SM + (slot) * 16384 + s_ * 8); } while (0)
#define STG_B256(slot, kbase, o) do { \
    const int s_ = (o) * 512 + tid; const int r_ = s_ >> 2; \
    const int q_ = (s_ & 3) ^ ((r_ >> 1) & 3); \
    gl2lds16(B + (size_t)(n0 + r_) * K + (kbase) + q_ * 8, \
             SM + (slot) * 16384 + 8192 + s_ * 8); } while (0)
#define DSA256(slot, row) (*(const bf16x8*)(SM + (slot) * 16384 + (row) * 32 + ((q2 ^ (((row) >> 1) & 3)) << 3)))
#define DSB256(slot, row) (*(const bf16x8*)(SM + (slot) * 16384 + 8192 + (row) * 32 + ((q2 ^ (((row) >> 1) & 3)) << 3)))
#define BAR256() asm volatile("s_barrier" ::: "memory")

    f32x4 acc[8][4];
    const f32x4 z4 = {0.f, 0.f, 0.f, 0.f};
#pragma unroll
    for (int i = 0; i < 8; i++)
#pragma unroll
        for (int j = 0; j < 4; j++) acc[i][j] = z4;

    STG_A256(0, 0, 0);  STG_A256(0, 0, 1);  STG_B256(0, 0, 0);  STG_B256(0, 0, 1);
    STG_A256(1, 32, 0); STG_A256(1, 32, 1); STG_B256(1, 32, 0); STG_B256(1, 32, 1);
    if (NT > 1) STG_A256(2, 64, 0);
    asm volatile("s_waitcnt vmcnt(5)" ::: "memory");
    BAR256();

    for (int t = 0; t < NT; ++t) {
        const int s0 = (2 * t) & 3, s1 = (2 * t + 1) & 3;
        const int sA = (2 * t + 2) & 3, sB = (2 * t + 3) & 3;
        const int kA = (t + 1) << 6, kB = kA + 32, kC = (t + 2) << 6;
        const bool stAB = (t < NT - 1), stC = (t < NT - 2);
        const int rA0 = wm * 128, rA1 = wm * 128 + 64, rB = wn * 64;
        bf16x8 a0[4], a1[4], b00[2], b01[2], b10[2], b11[2];

        // ---- p0
#pragma unroll
        for (int ii = 0; ii < 4; ii++) a0[ii] = DSA256(s0, rA0 + ii * 16 + ln);
        b00[0] = DSB256(s0, rB + ln);
        b00[1] = DSB256(s0, rB + 16 + ln);
        if (stAB) STG_A256(sA, kA, 1);
        __builtin_amdgcn_s_setprio(1);
#pragma unroll
        for (int ii = 0; ii < 4; ii++) {
            acc[ii][0] = MFMA16(a0[ii], b00[0], acc[ii][0]);
            acc[ii][1] = MFMA16(a0[ii], b00[1], acc[ii][1]);
        }
        __builtin_amdgcn_s_setprio(0);
        if (stAB) { asm volatile("s_waitcnt vmcnt(2)" ::: "memory"); }
        else      { asm volatile("s_waitcnt vmcnt(0)" ::: "memory"); }
        BAR256();

        // ---- p1
#pragma unroll
        for (int ii = 0; ii < 4; ii++) a1[ii] = DSA256(s1, rA0 + ii * 16 + ln);
        b01[0] = DSB256(s1, rB + ln);
        b01[1] = DSB256(s1, rB + 16 + ln);
        if (stAB) STG_B256(sA, kA, 0);
        __builtin_amdgcn_s_setprio(1);
#pragma unroll
        for (int ii = 0; ii < 4; ii++) {
            acc[ii][0] = MFMA16(a1[ii], b01[0], acc[ii][0]);
            acc[ii][1] = MFMA16(a1[ii], b01[1], acc[ii][1]);
        }
        __builtin_amdgcn_s_setprio(0);
        BAR256();

        // ---- p2
        b10[0] = DSB256(s0, rB + 32 + ln);
        b10[1] = DSB256(s0, rB + 48 + ln);
        if (stAB) STG_B256(sA, kA, 1);
        __builtin_amdgcn_s_setprio(1);
#pragma unroll
        for (int ii = 0; ii < 4; ii++) {
            acc[ii][2] = MFMA16(a0[ii], b10[0], acc[ii][2]);
            acc[ii][3] = MFMA16(a0[ii], b10[1], acc[ii][3]);
        }
        __builtin_amdgcn_s_setprio(0);
        BAR256();

        // ---- p3
        b11[0] = DSB256(s1, rB + 32 + ln);
        b11[1] = DSB256(s1, rB + 48 + ln);
        if (stAB) STG_A256(sB, kB, 0);
        __builtin_amdgcn_s_setprio(1);
#pragma unroll
        for (int ii = 0; ii < 4; ii++) {
            acc[ii][2] = MFMA16(a1[ii], b11[0], acc[ii][2]);
            acc[ii][3] = MFMA16(a1[ii], b11[1], acc[ii][3]);
        }
        __builtin_amdgcn_s_setprio(0);
        BAR256();

        // ---- p4
#pragma unroll
        for (int ii = 0; ii < 4; ii++) a0[ii] = DSA256(s0, rA1 + ii * 16 + ln);
        if (stAB) STG_A256(sB, kB, 1);
        __builtin_amdgcn_s_setprio(1);
#pragma unroll
        for (int ii = 0; ii < 4; ii++) {
            acc[4 + ii][2] = MFMA16(a0[ii], b10[0], acc[4 + ii][2]);
            acc[4 + ii][3] = MFMA16(a0[ii], b10[1], acc[4 + ii][3]);
        }
        __builtin_amdgcn_s_setprio(0);
        BAR256();

        // ---- p5
#pragma unroll
        for (int ii = 0; ii < 4; ii++) a1[ii] = DSA256(s1, rA1 + ii * 16 + ln);
        if (stAB) STG_B256(sB, kB, 0);
        __builtin_amdgcn_s_setprio(1);
#pragma unroll
        for (int ii = 0; ii < 4; ii++) {
            acc[4 + ii][2] = MFMA16(a1[ii], b11[0], acc[4 + ii][2]);
            acc[4 + ii][3] = MFMA16(a1[ii], b11[1], acc[4 + ii][3]);
        }
        __builtin_amdgcn_s_setprio(0);
        BAR256();

        // ---- p6
        if (stAB) STG_B256(sB, kB, 1);
        __builtin_amdgcn_s_setprio(1);
#pragma unroll
        for (int ii = 0; ii < 4; ii++) {
            acc[4 + ii][0] = MFMA16(a0[ii], b00[0], acc[4 + ii][0]);
            acc[4 + ii][1] = MFMA16(a0[ii], b00[1], acc[4 + ii][1]);
        }
        __builtin_amdgcn_s_setprio(0);
        BAR256();

        // ---- p7
        if (stC) STG_A256(s0, kC, 0);
        __builtin_amdgcn_s_setprio(1);
#pragma unroll
        for (int ii = 0; ii < 4; ii++) {
            acc[4 + ii][0] = MFMA16(a1[ii], b01[0], acc[4 + ii][0]);
            acc[4 + ii][1] = MFMA16(a1[ii], b01[1], acc[4 + ii][1]);
        }
        __builtin_amdgcn_s_setprio(0);
        if (t < NT - 2)       { asm volatile("s_waitcnt vmcnt(5)" ::: "memory"); }
        else if (t == NT - 2) { asm volatile("s_waitcnt vmcnt(4)" ::: "memory"); }
        BAR256();
    }

#pragma unroll
    for (int j = 0; j < 4; j++) {
        const int n = n0 + wn * 64 + j * 16 + ln;
        const float bv = bf2f(bias[n]);
#pragma unroll
        for (int i = 0; i < 8; i++) {
            const int mrow = m0 + wm * 128 + i * 16 + q2 * 4;
#pragma unroll
            for (int r = 0; r < 4; r++)
                C[(size_t)(mrow + r) * N + n] = f2bf(acc[i][j][r] + bv);
        }
    }
#undef STG_A256
#undef STG_B256
#undef DSA256
#undef DSB256
#undef BAR256
}

// ---------------------------------------------------------------------------
// Final GEMM: fp32 output when flag=1 (verified), bf16 otherwise. (m97-style)
// ---------------------------------------------------------------------------
__global__ __launch_bounds__(256) void gemm_bt_bias_out(
    const ushort_t* __restrict__ A, const ushort_t* __restrict__ B,
    const ushort_t* __restrict__ bias, void* __restrict__ C,
    int M, int N, int K, const int* __restrict__ flag)
{
    __shared__ __align__(16) ushort_t As[128 * 32];
    __shared__ __align__(16) ushort_t Bs[128 * 32];
    const int tid = threadIdx.x;
    const int w = tid >> 6, l = tid & 63, q = l >> 4, ln = l & 15;
    const int wm = w >> 1, wn = w & 1;
    const int m0 = blockIdx.y * 128, n0 = blockIdx.x * 128;
    const int sr = tid >> 2;
    const int sc = (tid & 3) * 8;

    f32x4 acc[4][4];
    const f32x4 z4 = {0.f, 0.f, 0.f, 0.f};
    for (int i = 0; i < 4; i++) for (int j = 0; j < 4; j++) acc[i][j] = z4;

    for (int k0 = 0; k0 < K; k0 += 32) {
        __syncthreads();
        gl2lds16(A + (size_t)(m0 + sr) * K + k0 + sc,       As + sr * 32 + sc);
        gl2lds16(A + (size_t)(m0 + 64 + sr) * K + k0 + sc,  As + (64 + sr) * 32 + sc);
        gl2lds16(B + (size_t)(n0 + sr) * K + k0 + sc,       Bs + sr * 32 + sc);
        gl2lds16(B + (size_t)(n0 + 64 + sr) * K + k0 + sc,  Bs + (64 + sr) * 32 + sc);
        __syncthreads();
        bf16x8 a[4], bb[4];
        for (int i = 0; i < 4; i++)
            a[i]  = *(const bf16x8*)(As + (wm * 64 + i * 16 + ln) * 32 + q * 8);
        for (int j = 0; j < 4; j++)
            bb[j] = *(const bf16x8*)(Bs + (wn * 64 + j * 16 + ln) * 32 + q * 8);
        for (int i = 0; i < 4; i++)
            for (int j = 0; j < 4; j++)
                acc[i][j] = MFMA16(a[i], bb[j], acc[i][j]);
    }
    const int f = flag[0];
    for (int j = 0; j < 4; j++) {
        const int n = n0 + wn * 64 + j * 16 + ln;
        const float bv = bf2f(bias[n]);
        for (int i = 0; i < 4; i++) {
            const int mrow = m0 + wm * 64 + i * 16 + q * 4;
            for (int r = 0; r < 4; r++) {
                const float val = acc[i][j][r] + bv;
                const size_t idx = (size_t)(mrow + r) * N + n;
                if (f) ((float*)C)[idx] = val;
                else   ((ushort_t*)C)[idx] = f2bf(val);
            }
        }
    }
}

// ---------------------------------------------------------------------------
// RoPE table: tab[s][k] = (cos, sin)(s * 10000^(-2k/2048)), s<2048, k<64.
// Bit-identical expressions to the verified in-kernel computation.
// Runs once per launch (after gemm256; lives in the dead Wqkvc tail).
// ---------------------------------------------------------------------------
__global__ __launch_bounds__(256) void rope_table_kernel(float* __restrict__ tab)
{
    const int idx = blockIdx.x * 256 + threadIdx.x;   // 512 blocks -> 131072
    const int s = idx >> 6, k = idx & 63;
    const float ang = powf(10000.0f, -(float)(2 * k) / 2048.0f);
    float sv, cv;
    sincosf((float)s * ang, &sv, &cv);
    tab[(size_t)idx * 2]     = cv;
    tab[(size_t)idx * 2 + 1] = sv;
}

// ---------------------------------------------------------------------------
// RoPE — ROUND-6: table-driven (was 8 powf + 8 sincosf per thread = VALU-bound;
// Appendix-B "precompute trig" rule). Same vectorized structure as round-5
// (verified): thread (head h, octet i) owns outputs [8i,8i+8) and [64+8i,+8).
// Table loads: k = 4i+e -> two f32x4 at tab[(s*64+4i)*2]; k+32 -> +64 floats.
// ---------------------------------------------------------------------------
__global__ __launch_bounds__(256) void rope_kernel(ushort_t* qkv, const float* __restrict__ tab)
{
    const int bs = blockIdx.x;
    const int s = bs & 2047;
    const int t = threadIdx.x;
    const int qk = t >> 7;              // 0 = Q, 1 = K
    const int u = t & 127;
    const int h = u >> 3, i = u & 7;
    ushort_t* row = qkv + (size_t)bs * 6144 + qk * 2048 + h * 128;

    union { bf16x8 v; ushort_t e[8]; } L0, L1, L2, L3;
    L0.v = *(const bf16x8*)(row + 8 * i);
    L1.v = *(const bf16x8*)(row + 64 + 8 * i);
    L2.v = *(const bf16x8*)(row + 16 * i);
    L3.v = *(const bf16x8*)(row + 16 * i + 8);

    const float* tA = tab + ((size_t)s * 64 + 4 * i) * 2;
    const f32x4 a0v = *(const f32x4*)(tA);
    const f32x4 a1v = *(const f32x4*)(tA + 4);
    const f32x4 b0v = *(const f32x4*)(tA + 64);
    const f32x4 b1v = *(const f32x4*)(tA + 68);
    const float ca[4]  = {a0v[0], a0v[2], a1v[0], a1v[2]};
    const float sa_[4] = {a0v[1], a0v[3], a1v[1], a1v[3]};
    const float cb[4]  = {b0v[0], b0v[2], b1v[0], b1v[2]};
    const float sb[4]  = {b0v[1], b0v[3], b1v[1], b1v[3]};

    __syncthreads();
    ushort_t oA[8], oB[8];
#pragma unroll
    for (int d = 0; d < 8; d++) {
        const int e = d >> 1;
        const float pA = (d < 4) ? bf2f(L2.e[2 * d + 1]) : bf2f(L3.e[2 * d - 7]);
        const float pB = (d < 4) ? bf2f(L2.e[2 * d])     : bf2f(L3.e[2 * d - 8]);
        oA[d] = f2bf(ca[e] * bf2f(L0.e[d]) - sa_[e] * pA);
        oB[d] = f2bf(cb[e] * bf2f(L1.e[d]) + sb[e] * pB);
    }
    *(bf16x8*)(row + 8 * i)      = *(const bf16x8*)oA;
    *(bf16x8*)(row + 64 + 8 * i) = *(const bf16x8*)oB;
}

// ---------------------------------------------------------------------------
// Vt[b,h,d,s] = qkv[b,s,2,h,d] (round-5 vectorized, verified).
// ---------------------------------------------------------------------------
__global__ __launch_bounds__(256) void vtrans_kernel(const ushort_t* __restrict__ qkv,
                                                     ushort_t* __restrict__ Vt)
{
    __shared__ __align__(16) ushort_t tile[64][136];
    const int blk = blockIdx.x;
    const int st = blk & 31, h = (blk >> 5) & 15, b = blk >> 9;
    const int t = threadIdx.x;
#pragma unroll
    for (int i = 0; i < 4; i++) {
        const int e = i * 256 + t;
        const int r = e >> 4, cb = e & 15;
        *(bf16x8*)(&tile[r][cb * 8]) =
            *(const bf16x8*)(qkv + (size_t)(b * 2048 + st * 64 + r) * 6144 + 4096 + h * 128 + cb * 8);
    }
    __syncthreads();
    const int d = t >> 1, s0 = (t & 1) * 32;
    const size_t obase = ((size_t)(b * 16 + h) * 128 + d) * 2048 + st * 64 + s0;
#pragma unroll
    for (int q4 = 0; q4 < 4; q4++) {
        ushort_t tmp[8];
#pragma unroll
        for (int j = 0; j < 8; j++) tmp[j] = tile[s0 + q4 * 8 + j][d];
        *(bf16x8*)(Vt + obase + q4 * 8) = *(const bf16x8*)tmp;
    }
}

// ---------------------------------------------------------------------------
// Flash attention v3 (round-1 verified math) — ROUND-6: XCD-aware 1-D grid.
// Bijective decode puts the 16 q-tile blocks of 4 (h,b) pairs on one XCD:
// per-XCD K/V working set = 4 x 1 MB = 4 MB = one XCD L2 (T1 mechanism).
// Order-only change: per-block computation identical -> bit-identical output.
// ---------------------------------------------------------------------------
__global__ __launch_bounds__(256, 2) void flash_kernel(
    const ushort_t* __restrict__ qkv, const ushort_t* __restrict__ Vt,
    const int* __restrict__ mask, ushort_t* __restrict__ AO)
{
    __shared__ __align__(16) ushort_t SM[16384];   // 32 KiB
    ushort_t* Ks = SM;          // [64][128] bf16, 16B-unit swizzle ^(row&15)
    ushort_t* Vs = SM + 8192;   // [128][64] bf16, 16B-unit swizzle ^(row&7)
    const int t = threadIdx.x;
    const int w = t >> 6, l = t & 63, lq = l & 31, q2 = l >> 5;
    // XCD-aware decode: xcd = bid&7 owns pairs p = xcd*4 .. xcd*4+3 (16 qtiles each)
    const int bid = blockIdx.x;
    const int xcd = bid & 7, ii = bid >> 3;
    const int p = xcd * 4 + (ii >> 4);
    const int qb = (ii & 15) * 128;
    const int h = p & 15, b = p >> 4;
    const size_t brow = (size_t)b * 2048;
    const float scale = 0.08838834764831845f;   // 1/sqrt(128)
    const int qrow = qb + w * 32 + lq;
    const size_t vbase = (size_t)(b * 16 + h) * 128;

    bf16x8 qf[8];
#pragma unroll
    for (int kb = 0; kb < 8; kb++)
        qf[kb] = *(const bf16x8*)(qkv + (brow + qrow) * 6144 + h * 128 + kb * 16 + q2 * 8);

    float m_old = -1e30f, lsum = 0.f;
    f32x16 acc_o[4];
#pragma unroll
    for (int dt = 0; dt < 4; dt++)
#pragma unroll
        for (int r = 0; r < 16; r++) acc_o[dt][r] = 0.f;

    bf16x8 kst[4], vst[4];
#pragma unroll
    for (int i = 0; i < 4; i++) {
        const int s_ = i * 256 + t; const int row = s_ >> 4; const int u = s_ & 15;
        kst[i] = *(const bf16x8*)(qkv + (brow + row) * 6144 + 2048 + h * 128 + u * 8);
    }
#pragma unroll
    for (int i = 0; i < 4; i++) {
        const int s_ = i * 256 + t; const int row = s_ >> 3; const int u = s_ & 7;
        vst[i] = *(const bf16x8*)(Vt + (vbase + row) * 2048 + u * 8);
    }

    for (int s0 = 0; s0 < 2048; s0 += 64) {
        const int mk = mask[brow + s0 + l];
        const unsigned long long bm = __ballot(mk != 0);
        asm volatile("s_waitcnt lgkmcnt(0)" ::: "memory");
        asm volatile("s_barrier" ::: "memory");          // all waves done reading prev tile
#pragma unroll
        for (int i = 0; i < 4; i++) {
            const int s_ = i * 256 + t; const int row = s_ >> 4; const int u = s_ & 15;
            *(bf16x8*)(Ks + row * 128 + ((u ^ (row & 15)) << 3)) = kst[i];
        }
#pragma unroll
        for (int i = 0; i < 4; i++) {
            const int s_ = i * 256 + t; const int row = s_ >> 3; const int u = s_ & 7;
            *(bf16x8*)(Vs + row * 64 + ((u ^ (row & 7)) << 3)) = vst[i];
        }
        if (s0 + 64 < 2048) {
#pragma unroll
            for (int i = 0; i < 4; i++) {
                const int s_ = i * 256 + t; const int row = s_ >> 4; const int u = s_ & 15;
                kst[i] = *(const bf16x8*)(qkv + (brow + s0 + 64 + row) * 6144 + 2048 + h * 128 + u * 8);
            }
#pragma unroll
            for (int i = 0; i < 4; i++) {
                const int s_ = i * 256 + t; const int row = s_ >> 3; const int u = s_ & 7;
                vst[i] = *(const bf16x8*)(Vt + (vbase + row) * 2048 + s0 + 64 + u * 8);
            }
        }
        asm volatile("s_waitcnt lgkmcnt(0)" ::: "memory");  // ds_writes drained (NOT vmcnt)
        asm volatile("s_barrier" ::: "memory");             // writes visible

        f32x16 sa[2];
#pragma unroll
        for (int mt = 0; mt < 2; mt++) {
#pragma unroll
            for (int r = 0; r < 16; r++) sa[mt][r] = 0.f;
            const int row = mt * 32 + lq;
            __builtin_amdgcn_s_setprio(1);
#pragma unroll
            for (int kb = 0; kb < 8; kb++) {
                bf16x8 a = *(const bf16x8*)(Ks + row * 128 + (((kb * 2 + q2) ^ (row & 15)) << 3));
                sa[mt] = MFMA32(a, qf[kb], sa[mt]);
            }
            __builtin_amdgcn_s_setprio(0);
        }
        float p_[32];
        float mr = -1e30f;
        if (bm == ~0ull) {
#pragma unroll
            for (int mt = 0; mt < 2; mt++)
#pragma unroll
                for (int r = 0; r < 16; r++) {
                    const float v = sa[mt][r] * scale;
                    p_[mt * 16 + r] = v;
                    mr = fmaxf(mr, v);
                }
        } else {
#pragma unroll
            for (int mt = 0; mt < 2; mt++)
#pragma unroll
                for (int r = 0; r < 16; r++) {
                    const int srow = mt * 32 + (r & 3) + 8 * (r >> 2) + 4 * q2;
                    const float bias = ((bm >> srow) & 1ull) ? 0.f : -1e9f;
                    const float v = sa[mt][r] * scale + bias;
                    p_[mt * 16 + r] = v;
                    mr = fmaxf(mr, v);
                }
        }
        mr = fmaxf(mr, __shfl_xor(mr, 32, 64));
        if (!__all(mr <= m_old + 8.0f)) {        // T13 defer-max
            const float mnew = fmaxf(m_old, mr);
            const float alpha = __expf(m_old - mnew);
            lsum *= alpha;
#pragma unroll
            for (int dt = 0; dt < 4; dt++)
#pragma unroll
                for (int r = 0; r < 16; r++) acc_o[dt][r] *= alpha;
            m_old = mnew;
        }
        float rs = 0.f;
#pragma unroll
        for (int i = 0; i < 32; i++) { p_[i] = __expf(p_[i] - m_old); rs += p_[i]; }
        rs += __shfl_xor(rs, 32, 64);
        lsum += rs;

#pragma unroll
        for (int kb = 0; kb < 4; kb++) {
            const int bb = (kb >> 1) * 16 + (kb & 1) * 8;
            unsigned w01, w23, w45, w67;
            asm("v_cvt_pk_bf16_f32 %0, %1, %2" : "=v"(w01) : "v"(p_[bb + 0]), "v"(p_[bb + 1]));
            asm("v_cvt_pk_bf16_f32 %0, %1, %2" : "=v"(w23) : "v"(p_[bb + 2]), "v"(p_[bb + 3]));
            asm("v_cvt_pk_bf16_f32 %0, %1, %2" : "=v"(w45) : "v"(p_[bb + 4]), "v"(p_[bb + 5]));
            asm("v_cvt_pk_bf16_f32 %0, %1, %2" : "=v"(w67) : "v"(p_[bb + 6]), "v"(p_[bb + 7]));
            asm("v_permlane32_swap_b32 %0, %1" : "+v"(w01), "+v"(w45));
            asm("v_permlane32_swap_b32 %0, %1" : "+v"(w23), "+v"(w67));
            union { unsigned u[4]; bf16x8 v8; } pu;
            pu.u[0] = w01; pu.u[1] = w23; pu.u[2] = w45; pu.u[3] = w67;
            __builtin_amdgcn_s_setprio(1);
#pragma unroll
            for (int dt = 0; dt < 4; dt++) {
                const int row = dt * 32 + lq;
                bf16x8 va = *(const bf16x8*)(Vs + row * 64 + (((kb * 2 + q2) ^ (row & 7)) << 3));
                acc_o[dt] = MFMA32(va, pu.v8, acc_o[dt]);
            }
            __builtin_amdgcn_s_setprio(0);
        }
    }
    __syncthreads();   // all PV reads done before epilogue overlays SM
    const float inv = (lsum > 0.f) ? 1.0f / lsum : 0.f;
#pragma unroll
    for (int dt = 0; dt < 4; dt++)
#pragma unroll
        for (int r2 = 0; r2 < 4; r2++) {
            us4 ov;
#pragma unroll
            for (int j = 0; j < 4; j++) ov[j] = f2bf(acc_o[dt][r2 * 4 + j] * inv);
            const int row = w * 32 + lq;
            const int unit = dt * 4 + r2;
            *(us4*)(SM + row * 128 + ((unit ^ (row & 15)) << 3) + q2 * 4) = ov;
        }
    __syncthreads();
#pragma unroll
    for (int i = 0; i < 8; i++) {
        const int rl = i * 4 + (l >> 4), ch = l & 15;
        const int row = w * 32 + rl;
        bf16x8 vv = *(const bf16x8*)(SM + row * 128 + ((ch ^ (row & 15)) << 3));
        *(bf16x8*)(AO + (brow + qb + row) * 2048 + h * 128 + ch * 8) = vv;
    }
}

extern "C" void kernel_launch(void* const* d_in, const int* in_sizes, int n_in,
                              void* d_out, int out_size, void* d_ws, size_t ws_size,
                              hipStream_t stream)
{
    (void)in_sizes; (void)n_in; (void)out_size; (void)ws_size;
    const void* X    = d_in[0];
    const int*  mask = (const int*)d_in[1];
    const void* Wqkv = d_in[2];
    const void* bqkv = d_in[3];
    const void* Wo   = d_in[4];
    const void* bo   = d_in[5];

    int*      flag  = (int*)d_ws;
    ushort_t* Xc    = (ushort_t*)d_ws + 16;
    ushort_t* Wqkvc = Xc + 8388608;
    ushort_t* bqkvc = Wqkvc + 12582912;
    ushort_t* Woc   = bqkvc + 6144;
    ushort_t* boc   = Woc + 4194304;
    ushort_t* qkv   = boc + 2048;
    ushort_t* Vt    = Wqkvc;                        // reuse: Wqkv dead after gemm1 (Vt = 8.39M ushorts)
    float*    rtab  = (float*)(Wqkvc + 8388608);    // Wqkvc tail beyond Vt: 4.19M ushorts free; table = 1MB
    ushort_t* AO    = Xc;                           // reuse: X dead after gemm1

    detect_kernel<<<1, 256, 0, stream>>>((const ushort_t*)Wqkv, flag);
    convert_kernel<<<4096, 256, 0, stream>>>(X,    Xc,    8388608,  flag);
    convert_kernel<<<6144, 256, 0, stream>>>(Wqkv, Wqkvc, 12582912, flag);
    convert_kernel<<<3,    256, 0, stream>>>(bqkv, bqkvc, 6144,     flag);
    convert_kernel<<<2048, 256, 0, stream>>>(Wo,   Woc,   4194304,  flag);
    convert_kernel<<<1,    256, 0, stream>>>(bo,   boc,   2048,     flag);

    gemm256_bt_bias<<<dim3(6144 / 256, 4096 / 256), 512, 0, stream>>>(Xc, Wqkvc, bqkvc, qkv, 4096, 6144, 2048);
    rope_table_kernel<<<512, 256, 0, stream>>>(rtab);    // after gemm256: Wqkvc tail now dead
    rope_kernel<<<4096, 256, 0, stream>>>(qkv, rtab);
    vtrans_kernel<<<1024, 256, 0, stream>>>(qkv, Vt);
    flash_kernel<<<512, 256, 0, stream>>>(qkv, Vt, mask, AO);
    gemm_bt_bias_out<<<dim3(2048 / 128, 4096 / 128), 256, 0, stream>>>(AO, Woc, boc, d_out, 4096, 2048, 2048, flag);
}

// Round 8
// 536.014 us; speedup vs baseline: 1.1500x; 1.0242x over previous
//
#include <hip/hip_runtime.h>
#include <hip/hip_bf16.h>
#include <math.h>

typedef __bf16 bf16x8 __attribute__((ext_vector_type(8)));
typedef float  f32x4  __attribute__((ext_vector_type(4)));
typedef float  f32x16 __attribute__((ext_vector_type(16)));
typedef unsigned short ushort_t;
typedef ushort_t us4 __attribute__((ext_vector_type(4)));

#define MFMA16(a, b, c) __builtin_amdgcn_mfma_f32_16x16x32_bf16((a), (b), (c), 0, 0, 0)
#define MFMA32(a, b, c) __builtin_amdgcn_mfma_f32_32x32x16_bf16((a), (b), (c), 0, 0, 0)

__device__ __forceinline__ float bf2f(ushort_t h) {
    union { unsigned u; float f; } v; v.u = ((unsigned)h) << 16; return v.f;
}
__device__ __forceinline__ ushort_t f2bf(float x) {
    union { float f; unsigned u; } v; v.f = x;
    unsigned r = v.u + 0x7FFFu + ((v.u >> 16) & 1u);
    return (ushort_t)(r >> 16);
}
// async global->LDS, 16B per lane. LDS dest must be wave-uniform base + lane*16.
__device__ __forceinline__ void gl2lds16(const void* g, void* l) {
    __builtin_amdgcn_global_load_lds((__attribute__((address_space(1))) void*)(g),
                                     (__attribute__((address_space(3))) void*)(l),
                                     16, 0, 0);
}

// ---------------------------------------------------------------------------
// Dtype detector (verified: flag=1 fires, inputs are fp32).
// ---------------------------------------------------------------------------
__global__ __launch_bounds__(256) void detect_kernel(const ushort_t* __restrict__ w, int* flag)
{
    __shared__ int cnt[256];
    const int t = threadIdx.x;
    int c = 0;
    for (int i = t; i < 65536; i += 256) {
        const unsigned hw = w[i];
        const unsigned e = (hw >> 7) & 0xFFu;
        if (e == 0xFFu || (e == 0u && (hw & 0x7Fu) != 0u)) c++;
    }
    cnt[t] = c;
    __syncthreads();
    for (int s = 128; s > 0; s >>= 1) {
        if (t < s) cnt[t] += cnt[t + s];
        __syncthreads();
    }
    if (t == 0) flag[0] = (cnt[0] >= 8) ? 1 : 0;
}

__global__ __launch_bounds__(256) void convert_kernel(const void* __restrict__ src,
                                                      ushort_t* __restrict__ dst,
                                                      int n, const int* __restrict__ flag)
{
    const int i0 = (blockIdx.x * 256 + threadIdx.x) * 8;
    if (i0 + 8 > n) return;
    if (flag[0]) {
        const f32x4 a = *(const f32x4*)((const float*)src + i0);
        const f32x4 b = *(const f32x4*)((const float*)src + i0 + 4);
        ushort_t o[8];
        o[0]=f2bf(a[0]); o[1]=f2bf(a[1]); o[2]=f2bf(a[2]); o[3]=f2bf(a[3]);
        o[4]=f2bf(b[0]); o[5]=f2bf(b[1]); o[6]=f2bf(b[2]); o[7]=f2bf(b[3]);
        *(bf16x8*)(dst + i0) = *(const bf16x8*)o;
    } else {
        *(bf16x8*)(dst + i0) = *(const bf16x8*)((const ushort_t*)src + i0);
    }
}

// ---------------------------------------------------------------------------
// 256x256-tile 8-phase GEMM, C = A * B^T + bias (bf16 in/out).
// K-loop: round-0 kernel verbatim (session best; restructures failed).
// ROUND-7: coalesced epilogue. Old C-write = 128 scalar 2B stores/thread ->
//   16-lane runs of 32B (1/4 cacheline); WRITE_SIZE showed 78MB vs 48MB ideal
//   (1.6x amplification). New: overlay the dead 128KB SM with the 256x256 bf16
//   output tile (exactly 128KB): ds_write_b16 per acc value (+bias, same f2bf,
//   same order -> bit-identical), barrier, then 16x b128 global stores/thread
//   (512B coalesced runs). LDS writes <=2 lanes/bank (free, m136).
// ---------------------------------------------------------------------------
__global__ __launch_bounds__(512, 2) void gemm256_bt_bias(
    const ushort_t* __restrict__ A, const ushort_t* __restrict__ B,
    const ushort_t* __restrict__ bias, ushort_t* __restrict__ C,
    int M, int N, int K)
{
    __shared__ __align__(16) ushort_t SM[65536];   // 4 slots x (8192 A + 8192 B) ushorts
    const int tid = threadIdx.x;
    const int l = tid & 63, ln = l & 15, q2 = l >> 4;
    const int w = tid >> 6, wm = w >> 2, wn = w & 3;
    const int m0 = blockIdx.y * 256, n0 = blockIdx.x * 256;
    const int NT = K >> 6;

#define STG_A256(slot, kbase, o) do { \
    const int s_ = (o) * 512 + tid; const int r_ = s_ >> 2; \
    const int q_ = (s_ & 3) ^ ((r_ >> 1) & 3); \
    gl2lds16(A + (size_t)(m0 + r_) * K + (kbase) + q_ * 8, \
             SM + (slot) * 16384 + s_ * 8); } while (0)
#define STG_B256(slot, kbase, o) do { \
    const int s_ = (o) * 512 + tid; const int r_ = s_ >> 2; \
    const int q_ = (s_ & 3) ^ ((r_ >> 1) & 3); \
    gl2lds16(B + (size_t)(n0 + r_) * K + (kbase) + q_ * 8, \
             SM + (slot) * 16384 + 8192 + s_ * 8); } while (0)
#define DSA256(slot, row) (*(const bf16x8*)(SM + (slot) * 16384 + (row) * 32 + ((q2 ^ (((row) >> 1) & 3)) << 3)))
#define DSB256(slot, row) (*(const bf16x8*)(SM + (slot) * 16384 + 8192 + (row) * 32 + ((q2 ^ (((row) >> 1) & 3)) << 3)))
#define BAR256() asm volatile("s_barrier" ::: "memory")

    f32x4 acc[8][4];
    const f32x4 z4 = {0.f, 0.f, 0.f, 0.f};
#pragma unroll
    for (int i = 0; i < 8; i++)
#pragma unroll
        for (int j = 0; j < 4; j++) acc[i][j] = z4;

    STG_A256(0, 0, 0);  STG_A256(0, 0, 1);  STG_B256(0, 0, 0);  STG_B256(0, 0, 1);
    STG_A256(1, 32, 0); STG_A256(1, 32, 1); STG_B256(1, 32, 0); STG_B256(1, 32, 1);
    if (NT > 1) STG_A256(2, 64, 0);
    asm volatile("s_waitcnt vmcnt(5)" ::: "memory");
    BAR256();

    for (int t = 0; t < NT; ++t) {
        const int s0 = (2 * t) & 3, s1 = (2 * t + 1) & 3;
        const int sA = (2 * t + 2) & 3, sB = (2 * t + 3) & 3;
        const int kA = (t + 1) << 6, kB = kA + 32, kC = (t + 2) << 6;
        const bool stAB = (t < NT - 1), stC = (t < NT - 2);
        const int rA0 = wm * 128, rA1 = wm * 128 + 64, rB = wn * 64;
        bf16x8 a0[4], a1[4], b00[2], b01[2], b10[2], b11[2];

        // ---- p0
#pragma unroll
        for (int ii = 0; ii < 4; ii++) a0[ii] = DSA256(s0, rA0 + ii * 16 + ln);
        b00[0] = DSB256(s0, rB + ln);
        b00[1] = DSB256(s0, rB + 16 + ln);
        if (stAB) STG_A256(sA, kA, 1);
        __builtin_amdgcn_s_setprio(1);
#pragma unroll
        for (int ii = 0; ii < 4; ii++) {
            acc[ii][0] = MFMA16(a0[ii], b00[0], acc[ii][0]);
            acc[ii][1] = MFMA16(a0[ii], b00[1], acc[ii][1]);
        }
        __builtin_amdgcn_s_setprio(0);
        if (stAB) { asm volatile("s_waitcnt vmcnt(2)" ::: "memory"); }
        else      { asm volatile("s_waitcnt vmcnt(0)" ::: "memory"); }
        BAR256();

        // ---- p1
#pragma unroll
        for (int ii = 0; ii < 4; ii++) a1[ii] = DSA256(s1, rA0 + ii * 16 + ln);
        b01[0] = DSB256(s1, rB + ln);
        b01[1] = DSB256(s1, rB + 16 + ln);
        if (stAB) STG_B256(sA, kA, 0);
        __builtin_amdgcn_s_setprio(1);
#pragma unroll
        for (int ii = 0; ii < 4; ii++) {
            acc[ii][0] = MFMA16(a1[ii], b01[0], acc[ii][0]);
            acc[ii][1] = MFMA16(a1[ii], b01[1], acc[ii][1]);
        }
        __builtin_amdgcn_s_setprio(0);
        BAR256();

        // ---- p2
        b10[0] = DSB256(s0, rB + 32 + ln);
        b10[1] = DSB256(s0, rB + 48 + ln);
        if (stAB) STG_B256(sA, kA, 1);
        __builtin_amdgcn_s_setprio(1);
#pragma unroll
        for (int ii = 0; ii < 4; ii++) {
            acc[ii][2] = MFMA16(a0[ii], b10[0], acc[ii][2]);
            acc[ii][3] = MFMA16(a0[ii], b10[1], acc[ii][3]);
        }
        __builtin_amdgcn_s_setprio(0);
        BAR256();

        // ---- p3
        b11[0] = DSB256(s1, rB + 32 + ln);
        b11[1] = DSB256(s1, rB + 48 + ln);
        if (stAB) STG_A256(sB, kB, 0);
        __builtin_amdgcn_s_setprio(1);
#pragma unroll
        for (int ii = 0; ii < 4; ii++) {
            acc[ii][2] = MFMA16(a1[ii], b11[0], acc[ii][2]);
            acc[ii][3] = MFMA16(a1[ii], b11[1], acc[ii][3]);
        }
        __builtin_amdgcn_s_setprio(0);
        BAR256();

        // ---- p4
#pragma unroll
        for (int ii = 0; ii < 4; ii++) a0[ii] = DSA256(s0, rA1 + ii * 16 + ln);
        if (stAB) STG_A256(sB, kB, 1);
        __builtin_amdgcn_s_setprio(1);
#pragma unroll
        for (int ii = 0; ii < 4; ii++) {
            acc[4 + ii][2] = MFMA16(a0[ii], b10[0], acc[4 + ii][2]);
            acc[4 + ii][3] = MFMA16(a0[ii], b10[1], acc[4 + ii][3]);
        }
        __builtin_amdgcn_s_setprio(0);
        BAR256();

        // ---- p5
#pragma unroll
        for (int ii = 0; ii < 4; ii++) a1[ii] = DSA256(s1, rA1 + ii * 16 + ln);
        if (stAB) STG_B256(sB, kB, 0);
        __builtin_amdgcn_s_setprio(1);
#pragma unroll
        for (int ii = 0; ii < 4; ii++) {
            acc[4 + ii][2] = MFMA16(a1[ii], b11[0], acc[4 + ii][2]);
            acc[4 + ii][3] = MFMA16(a1[ii], b11[1], acc[4 + ii][3]);
        }
        __builtin_amdgcn_s_setprio(0);
        BAR256();

        // ---- p6
        if (stAB) STG_B256(sB, kB, 1);
        __builtin_amdgcn_s_setprio(1);
#pragma unroll
        for (int ii = 0; ii < 4; ii++) {
            acc[4 + ii][0] = MFMA16(a0[ii], b00[0], acc[4 + ii][0]);
            acc[4 + ii][1] = MFMA16(a0[ii], b00[1], acc[4 + ii][1]);
        }
        __builtin_amdgcn_s_setprio(0);
        BAR256();

        // ---- p7
        if (stC) STG_A256(s0, kC, 0);
        __builtin_amdgcn_s_setprio(1);
#pragma unroll
        for (int ii = 0; ii < 4; ii++) {
            acc[4 + ii][0] = MFMA16(a1[ii], b01[0], acc[4 + ii][0]);
            acc[4 + ii][1] = MFMA16(a1[ii], b01[1], acc[4 + ii][1]);
        }
        __builtin_amdgcn_s_setprio(0);
        if (t < NT - 2)       { asm volatile("s_waitcnt vmcnt(5)" ::: "memory"); }
        else if (t == NT - 2) { asm volatile("s_waitcnt vmcnt(4)" ::: "memory"); }
        BAR256();
    }

    // ---- ROUND-7 epilogue: LDS transpose-stage -> coalesced b128 stores.
    __syncthreads();   // K-loop LDS fully dead before overlay
#pragma unroll
    for (int j = 0; j < 4; j++) {
        const int nloc = wn * 64 + j * 16 + ln;
        const float bv = bf2f(bias[n0 + nloc]);
#pragma unroll
        for (int i = 0; i < 8; i++) {
            const int rloc = wm * 128 + i * 16 + q2 * 4;
#pragma unroll
            for (int r = 0; r < 4; r++)
                SM[(rloc + r) * 256 + nloc] = f2bf(acc[i][j][r] + bv);
        }
    }
    __syncthreads();
#pragma unroll
    for (int k = 0; k < 16; k++) {
        const int e = k * 512 + tid;
        const int row = e >> 5, unit = e & 31;
        *(bf16x8*)(C + (size_t)(m0 + row) * N + n0 + unit * 8) =
            *(const bf16x8*)(SM + row * 256 + unit * 8);
    }
#undef STG_A256
#undef STG_B256
#undef DSA256
#undef DSB256
#undef BAR256
}

// ---------------------------------------------------------------------------
// Final GEMM: fp32 output when flag=1 (verified), bf16 otherwise. (m97-style)
// ROUND-7: XCD-chunked block remap (order-only). All 512 blocks co-resident at
// 2/CU; chunking gives each XCD 4 m-tiles x all n -> working set 17->10MB.
// ---------------------------------------------------------------------------
__global__ __launch_bounds__(256) void gemm_bt_bias_out(
    const ushort_t* __restrict__ A, const ushort_t* __restrict__ B,
    const ushort_t* __restrict__ bias, void* __restrict__ C,
    int M, int N, int K, const int* __restrict__ flag)
{
    __shared__ __align__(16) ushort_t As[128 * 32];
    __shared__ __align__(16) ushort_t Bs[128 * 32];
    const int tid = threadIdx.x;
    const int w = tid >> 6, l = tid & 63, q = l >> 4, ln = l & 15;
    const int wm = w >> 1, wn = w & 1;
    // XCD-chunked remap: lin -> xcd owns 64 consecutive nlin (4 m-tiles x 16 n)
    const int lin = blockIdx.y * 16 + blockIdx.x;   // gridDim.x == 16
    const int nlin = (lin & 7) * 64 + (lin >> 3);
    const int m0 = (nlin >> 4) * 128, n0 = (nlin & 15) * 128;
    const int sr = tid >> 2;
    const int sc = (tid & 3) * 8;

    f32x4 acc[4][4];
    const f32x4 z4 = {0.f, 0.f, 0.f, 0.f};
    for (int i = 0; i < 4; i++) for (int j = 0; j < 4; j++) acc[i][j] = z4;

    for (int k0 = 0; k0 < K; k0 += 32) {
        __syncthreads();
        gl2lds16(A + (size_t)(m0 + sr) * K + k0 + sc,       As + sr * 32 + sc);
        gl2lds16(A + (size_t)(m0 + 64 + sr) * K + k0 + sc,  As + (64 + sr) * 32 + sc);
        gl2lds16(B + (size_t)(n0 + sr) * K + k0 + sc,       Bs + sr * 32 + sc);
        gl2lds16(B + (size_t)(n0 + 64 + sr) * K + k0 + sc,  Bs + (64 + sr) * 32 + sc);
        __syncthreads();
        bf16x8 a[4], bb[4];
        for (int i = 0; i < 4; i++)
            a[i]  = *(const bf16x8*)(As + (wm * 64 + i * 16 + ln) * 32 + q * 8);
        for (int j = 0; j < 4; j++)
            bb[j] = *(const bf16x8*)(Bs + (wn * 64 + j * 16 + ln) * 32 + q * 8);
        for (int i = 0; i < 4; i++)
            for (int j = 0; j < 4; j++)
                acc[i][j] = MFMA16(a[i], bb[j], acc[i][j]);
    }
    const int f = flag[0];
    for (int j = 0; j < 4; j++) {
        const int n = n0 + wn * 64 + j * 16 + ln;
        const float bv = bf2f(bias[n]);
        for (int i = 0; i < 4; i++) {
            const int mrow = m0 + wm * 64 + i * 16 + q * 4;
            for (int r = 0; r < 4; r++) {
                const float val = acc[i][j][r] + bv;
                const size_t idx = (size_t)(mrow + r) * N + n;
                if (f) ((float*)C)[idx] = val;
                else   ((ushort_t*)C)[idx] = f2bf(val);
            }
        }
    }
}

// ---------------------------------------------------------------------------
// RoPE table: tab[s][k] = (cos, sin)(s * 10000^(-2k/2048)), s<2048, k<64.
// Bit-identical expressions to the verified in-kernel computation.
// ---------------------------------------------------------------------------
__global__ __launch_bounds__(256) void rope_table_kernel(float* __restrict__ tab)
{
    const int idx = blockIdx.x * 256 + threadIdx.x;   // 512 blocks -> 131072
    const int s = idx >> 6, k = idx & 63;
    const float ang = powf(10000.0f, -(float)(2 * k) / 2048.0f);
    float sv, cv;
    sincosf((float)s * ang, &sv, &cv);
    tab[(size_t)idx * 2]     = cv;
    tab[(size_t)idx * 2 + 1] = sv;
}

// ---------------------------------------------------------------------------
// RoPE — table-driven (round-6, verified).
// ---------------------------------------------------------------------------
__global__ __launch_bounds__(256) void rope_kernel(ushort_t* qkv, const float* __restrict__ tab)
{
    const int bs = blockIdx.x;
    const int s = bs & 2047;
    const int t = threadIdx.x;
    const int qk = t >> 7;              // 0 = Q, 1 = K
    const int u = t & 127;
    const int h = u >> 3, i = u & 7;
    ushort_t* row = qkv + (size_t)bs * 6144 + qk * 2048 + h * 128;

    union { bf16x8 v; ushort_t e[8]; } L0, L1, L2, L3;
    L0.v = *(const bf16x8*)(row + 8 * i);
    L1.v = *(const bf16x8*)(row + 64 + 8 * i);
    L2.v = *(const bf16x8*)(row + 16 * i);
    L3.v = *(const bf16x8*)(row + 16 * i + 8);

    const float* tA = tab + ((size_t)s * 64 + 4 * i) * 2;
    const f32x4 a0v = *(const f32x4*)(tA);
    const f32x4 a1v = *(const f32x4*)(tA + 4);
    const f32x4 b0v = *(const f32x4*)(tA + 64);
    const f32x4 b1v = *(const f32x4*)(tA + 68);
    const float ca[4]  = {a0v[0], a0v[2], a1v[0], a1v[2]};
    const float sa_[4] = {a0v[1], a0v[3], a1v[1], a1v[3]};
    const float cb[4]  = {b0v[0], b0v[2], b1v[0], b1v[2]};
    const float sb[4]  = {b0v[1], b0v[3], b1v[1], b1v[3]};

    __syncthreads();
    ushort_t oA[8], oB[8];
#pragma unroll
    for (int d = 0; d < 8; d++) {
        const int e = d >> 1;
        const float pA = (d < 4) ? bf2f(L2.e[2 * d + 1]) : bf2f(L3.e[2 * d - 7]);
        const float pB = (d < 4) ? bf2f(L2.e[2 * d])     : bf2f(L3.e[2 * d - 8]);
        oA[d] = f2bf(ca[e] * bf2f(L0.e[d]) - sa_[e] * pA);
        oB[d] = f2bf(cb[e] * bf2f(L1.e[d]) + sb[e] * pB);
    }
    *(bf16x8*)(row + 8 * i)      = *(const bf16x8*)oA;
    *(bf16x8*)(row + 64 + 8 * i) = *(const bf16x8*)oB;
}

// ---------------------------------------------------------------------------
// Vt[b,h,d,s] = qkv[b,s,2,h,d] (round-5 vectorized, verified).
// ---------------------------------------------------------------------------
__global__ __launch_bounds__(256) void vtrans_kernel(const ushort_t* __restrict__ qkv,
                                                     ushort_t* __restrict__ Vt)
{
    __shared__ __align__(16) ushort_t tile[64][136];
    const int blk = blockIdx.x;
    const int st = blk & 31, h = (blk >> 5) & 15, b = blk >> 9;
    const int t = threadIdx.x;
#pragma unroll
    for (int i = 0; i < 4; i++) {
        const int e = i * 256 + t;
        const int r = e >> 4, cb = e & 15;
        *(bf16x8*)(&tile[r][cb * 8]) =
            *(const bf16x8*)(qkv + (size_t)(b * 2048 + st * 64 + r) * 6144 + 4096 + h * 128 + cb * 8);
    }
    __syncthreads();
    const int d = t >> 1, s0 = (t & 1) * 32;
    const size_t obase = ((size_t)(b * 16 + h) * 128 + d) * 2048 + st * 64 + s0;
#pragma unroll
    for (int q4 = 0; q4 < 4; q4++) {
        ushort_t tmp[8];
#pragma unroll
        for (int j = 0; j < 8; j++) tmp[j] = tile[s0 + q4 * 8 + j][d];
        *(bf16x8*)(Vt + obase + q4 * 8) = *(const bf16x8*)tmp;
    }
}

// ---------------------------------------------------------------------------
// Flash attention v3 (round-6, verified): swizzled Ks/Vs, T14 async-STAGE,
// T12 in-register P, T13 defer-max, setprio, XCD-aware 1-D grid.
// ---------------------------------------------------------------------------
__global__ __launch_bounds__(256, 2) void flash_kernel(
    const ushort_t* __restrict__ qkv, const ushort_t* __restrict__ Vt,
    const int* __restrict__ mask, ushort_t* __restrict__ AO)
{
    __shared__ __align__(16) ushort_t SM[16384];   // 32 KiB
    ushort_t* Ks = SM;          // [64][128] bf16, 16B-unit swizzle ^(row&15)
    ushort_t* Vs = SM + 8192;   // [128][64] bf16, 16B-unit swizzle ^(row&7)
    const int t = threadIdx.x;
    const int w = t >> 6, l = t & 63, lq = l & 31, q2 = l >> 5;
    const int bid = blockIdx.x;
    const int xcd = bid & 7, ii = bid >> 3;
    const int p = xcd * 4 + (ii >> 4);
    const int qb = (ii & 15) * 128;
    const int h = p & 15, b = p >> 4;
    const size_t brow = (size_t)b * 2048;
    const float scale = 0.08838834764831845f;   // 1/sqrt(128)
    const int qrow = qb + w * 32 + lq;
    const size_t vbase = (size_t)(b * 16 + h) * 128;

    bf16x8 qf[8];
#pragma unroll
    for (int kb = 0; kb < 8; kb++)
        qf[kb] = *(const bf16x8*)(qkv + (brow + qrow) * 6144 + h * 128 + kb * 16 + q2 * 8);

    float m_old = -1e30f, lsum = 0.f;
    f32x16 acc_o[4];
#pragma unroll
    for (int dt = 0; dt < 4; dt++)
#pragma unroll
        for (int r = 0; r < 16; r++) acc_o[dt][r] = 0.f;

    bf16x8 kst[4], vst[4];
#pragma unroll
    for (int i = 0; i < 4; i++) {
        const int s_ = i * 256 + t; const int row = s_ >> 4; const int u = s_ & 15;
        kst[i] = *(const bf16x8*)(qkv + (brow + row) * 6144 + 2048 + h * 128 + u * 8);
    }
#pragma unroll
    for (int i = 0; i < 4; i++) {
        const int s_ = i * 256 + t; const int row = s_ >> 3; const int u = s_ & 7;
        vst[i] = *(const bf16x8*)(Vt + (vbase + row) * 2048 + u * 8);
    }

    for (int s0 = 0; s0 < 2048; s0 += 64) {
        const int mk = mask[brow + s0 + l];
        const unsigned long long bm = __ballot(mk != 0);
        asm volatile("s_waitcnt lgkmcnt(0)" ::: "memory");
        asm volatile("s_barrier" ::: "memory");          // all waves done reading prev tile
#pragma unroll
        for (int i = 0; i < 4; i++) {
            const int s_ = i * 256 + t; const int row = s_ >> 4; const int u = s_ & 15;
            *(bf16x8*)(Ks + row * 128 + ((u ^ (row & 15)) << 3)) = kst[i];
        }
#pragma unroll
        for (int i = 0; i < 4; i++) {
            const int s_ = i * 256 + t; const int row = s_ >> 3; const int u = s_ & 7;
            *(bf16x8*)(Vs + row * 64 + ((u ^ (row & 7)) << 3)) = vst[i];
        }
        if (s0 + 64 < 2048) {
#pragma unroll
            for (int i = 0; i < 4; i++) {
                const int s_ = i * 256 + t; const int row = s_ >> 4; const int u = s_ & 15;
                kst[i] = *(const bf16x8*)(qkv + (brow + s0 + 64 + row) * 6144 + 2048 + h * 128 + u * 8);
            }
#pragma unroll
            for (int i = 0; i < 4; i++) {
                const int s_ = i * 256 + t; const int row = s_ >> 3; const int u = s_ & 7;
                vst[i] = *(const bf16x8*)(Vt + (vbase + row) * 2048 + s0 + 64 + u * 8);
            }
        }
        asm volatile("s_waitcnt lgkmcnt(0)" ::: "memory");  // ds_writes drained (NOT vmcnt)
        asm volatile("s_barrier" ::: "memory");             // writes visible

        f32x16 sa[2];
#pragma unroll
        for (int mt = 0; mt < 2; mt++) {
#pragma unroll
            for (int r = 0; r < 16; r++) sa[mt][r] = 0.f;
            const int row = mt * 32 + lq;
            __builtin_amdgcn_s_setprio(1);
#pragma unroll
            for (int kb = 0; kb < 8; kb++) {
                bf16x8 a = *(const bf16x8*)(Ks + row * 128 + (((kb * 2 + q2) ^ (row & 15)) << 3));
                sa[mt] = MFMA32(a, qf[kb], sa[mt]);
            }
            __builtin_amdgcn_s_setprio(0);
        }
        float p_[32];
        float mr = -1e30f;
        if (bm == ~0ull) {
#pragma unroll
            for (int mt = 0; mt < 2; mt++)
#pragma unroll
                for (int r = 0; r < 16; r++) {
                    const float v = sa[mt][r] * scale;
                    p_[mt * 16 + r] = v;
                    mr = fmaxf(mr, v);
                }
        } else {
#pragma unroll
            for (int mt = 0; mt < 2; mt++)
#pragma unroll
                for (int r = 0; r < 16; r++) {
                    const int srow = mt * 32 + (r & 3) + 8 * (r >> 2) + 4 * q2;
                    const float bias = ((bm >> srow) & 1ull) ? 0.f : -1e9f;
                    const float v = sa[mt][r] * scale + bias;
                    p_[mt * 16 + r] = v;
                    mr = fmaxf(mr, v);
                }
        }
        mr = fmaxf(mr, __shfl_xor(mr, 32, 64));
        if (!__all(mr <= m_old + 8.0f)) {        // T13 defer-max
            const float mnew = fmaxf(m_old, mr);
            const float alpha = __expf(m_old - mnew);
            lsum *= alpha;
#pragma unroll
            for (int dt = 0; dt < 4; dt++)
#pragma unroll
                for (int r = 0; r < 16; r++) acc_o[dt][r] *= alpha;
            m_old = mnew;
        }
        float rs = 0.f;
#pragma unroll
        for (int i = 0; i < 32; i++) { p_[i] = __expf(p_[i] - m_old); rs += p_[i]; }
        rs += __shfl_xor(rs, 32, 64);
        lsum += rs;

#pragma unroll
        for (int kb = 0; kb < 4; kb++) {
            const int bb = (kb >> 1) * 16 + (kb & 1) * 8;
            unsigned w01, w23, w45, w67;
            asm("v_cvt_pk_bf16_f32 %0, %1, %2" : "=v"(w01) : "v"(p_[bb + 0]), "v"(p_[bb + 1]));
            asm("v_cvt_pk_bf16_f32 %0, %1, %2" : "=v"(w23) : "v"(p_[bb + 2]), "v"(p_[bb + 3]));
            asm("v_cvt_pk_bf16_f32 %0, %1, %2" : "=v"(w45) : "v"(p_[bb + 4]), "v"(p_[bb + 5]));
            asm("v_cvt_pk_bf16_f32 %0, %1, %2" : "=v"(w67) : "v"(p_[bb + 6]), "v"(p_[bb + 7]));
            asm("v_permlane32_swap_b32 %0, %1" : "+v"(w01), "+v"(w45));
            asm("v_permlane32_swap_b32 %0, %1" : "+v"(w23), "+v"(w67));
            union { unsigned u[4]; bf16x8 v8; } pu;
            pu.u[0] = w01; pu.u[1] = w23; pu.u[2] = w45; pu.u[3] = w67;
            __builtin_amdgcn_s_setprio(1);
#pragma unroll
            for (int dt = 0; dt < 4; dt++) {
                const int row = dt * 32 + lq;
                bf16x8 va = *(const bf16x8*)(Vs + row * 64 + (((kb * 2 + q2) ^ (row & 7)) << 3));
                acc_o[dt] = MFMA32(va, pu.v8, acc_o[dt]);
            }
            __builtin_amdgcn_s_setprio(0);
        }
    }
    __syncthreads();   // all PV reads done before epilogue overlays SM
    const float inv = (lsum > 0.f) ? 1.0f / lsum : 0.f;
#pragma unroll
    for (int dt = 0; dt < 4; dt++)
#pragma unroll
        for (int r2 = 0; r2 < 4; r2++) {
            us4 ov;
#pragma unroll
            for (int j = 0; j < 4; j++) ov[j] = f2bf(acc_o[dt][r2 * 4 + j] * inv);
            const int row = w * 32 + lq;
            const int unit = dt * 4 + r2;
            *(us4*)(SM + row * 128 + ((unit ^ (row & 15)) << 3) + q2 * 4) = ov;
        }
    __syncthreads();
#pragma unroll
    for (int i = 0; i < 8; i++) {
        const int rl = i * 4 + (l >> 4), ch = l & 15;
        const int row = w * 32 + rl;
        bf16x8 vv = *(const bf16x8*)(SM + row * 128 + ((ch ^ (row & 15)) << 3));
        *(bf16x8*)(AO + (brow + qb + row) * 2048 + h * 128 + ch * 8) = vv;
    }
}

extern "C" void kernel_launch(void* const* d_in, const int* in_sizes, int n_in,
                              void* d_out, int out_size, void* d_ws, size_t ws_size,
                              hipStream_t stream)
{
    (void)in_sizes; (void)n_in; (void)out_size; (void)ws_size;
    const void* X    = d_in[0];
    const int*  mask = (const int*)d_in[1];
    const void* Wqkv = d_in[2];
    const void* bqkv = d_in[3];
    const void* Wo   = d_in[4];
    const void* bo   = d_in[5];

    int*      flag  = (int*)d_ws;
    ushort_t* Xc    = (ushort_t*)d_ws + 16;
    ushort_t* Wqkvc = Xc + 8388608;
    ushort_t* bqkvc = Wqkvc + 12582912;
    ushort_t* Woc   = bqkvc + 6144;
    ushort_t* boc   = Woc + 4194304;
    ushort_t* qkv   = boc + 2048;
    ushort_t* Vt    = Wqkvc;                        // reuse: Wqkv dead after gemm1 (Vt = 8.39M ushorts)
    float*    rtab  = (float*)(Wqkvc + 8388608);    // Wqkvc tail beyond Vt: 4.19M ushorts free; table = 1MB
    ushort_t* AO    = Xc;                           // reuse: X dead after gemm1

    detect_kernel<<<1, 256, 0, stream>>>((const ushort_t*)Wqkv, flag);
    convert_kernel<<<4096, 256, 0, stream>>>(X,    Xc,    8388608,  flag);
    convert_kernel<<<6144, 256, 0, stream>>>(Wqkv, Wqkvc, 12582912, flag);
    convert_kernel<<<3,    256, 0, stream>>>(bqkv, bqkvc, 6144,     flag);
    convert_kernel<<<2048, 256, 0, stream>>>(Wo,   Woc,   4194304,  flag);
    convert_kernel<<<1,    256, 0, stream>>>(bo,   boc,   2048,     flag);

    gemm256_bt_bias<<<dim3(6144 / 256, 4096 / 256), 512, 0, stream>>>(Xc, Wqkvc, bqkvc, qkv, 4096, 6144, 2048);
    rope_table_kernel<<<512, 256, 0, stream>>>(rtab);    // after gemm256: Wqkvc tail now dead
    rope_kernel<<<4096, 256, 0, stream>>>(qkv, rtab);
    vtrans_kernel<<<1024, 256, 0, stream>>>(qkv, Vt);
    flash_kernel<<<512, 256, 0, stream>>>(qkv, Vt, mask, AO);
    gemm_bt_bias_out<<<dim3(2048 / 128, 4096 / 128), 256, 0, stream>>>(AO, Woc, boc, d_out, 4096, 2048, 2048, flag);
}

// Round 9
// 528.233 us; speedup vs baseline: 1.1669x; 1.0147x over previous
//
#include <hip/hip_runtime.h>
#include <hip/hip_bf16.h>
#include <math.h>

typedef __bf16 bf16x8 __attribute__((ext_vector_type(8)));
typedef float  f32x4  __attribute__((ext_vector_type(4)));
typedef float  f32x16 __attribute__((ext_vector_type(16)));
typedef unsigned short ushort_t;
typedef ushort_t us4 __attribute__((ext_vector_type(4)));

#define MFMA16(a, b, c) __builtin_amdgcn_mfma_f32_16x16x32_bf16((a), (b), (c), 0, 0, 0)
#define MFMA32(a, b, c) __builtin_amdgcn_mfma_f32_32x32x16_bf16((a), (b), (c), 0, 0, 0)

__device__ __forceinline__ float bf2f(ushort_t h) {
    union { unsigned u; float f; } v; v.u = ((unsigned)h) << 16; return v.f;
}
__device__ __forceinline__ ushort_t f2bf(float x) {
    union { float f; unsigned u; } v; v.f = x;
    unsigned r = v.u + 0x7FFFu + ((v.u >> 16) & 1u);
    return (ushort_t)(r >> 16);
}
// async global->LDS, 16B per lane. LDS dest must be wave-uniform base + lane*16.
__device__ __forceinline__ void gl2lds16(const void* g, void* l) {
    __builtin_amdgcn_global_load_lds((__attribute__((address_space(1))) void*)(g),
                                     (__attribute__((address_space(3))) void*)(l),
                                     16, 0, 0);
}

// ---------------------------------------------------------------------------
// Dtype detector (verified: flag=1 fires, inputs are fp32).
// ---------------------------------------------------------------------------
__global__ __launch_bounds__(256) void detect_kernel(const ushort_t* __restrict__ w, int* flag)
{
    __shared__ int cnt[256];
    const int t = threadIdx.x;
    int c = 0;
    for (int i = t; i < 65536; i += 256) {
        const unsigned hw = w[i];
        const unsigned e = (hw >> 7) & 0xFFu;
        if (e == 0xFFu || (e == 0u && (hw & 0x7Fu) != 0u)) c++;
    }
    cnt[t] = c;
    __syncthreads();
    for (int s = 128; s > 0; s >>= 1) {
        if (t < s) cnt[t] += cnt[t + s];
        __syncthreads();
    }
    if (t == 0) flag[0] = (cnt[0] >= 8) ? 1 : 0;
}

// ---------------------------------------------------------------------------
// ROUND-8: all 5 dtype-convert launches fused into one (block-range dispatch).
// Body is byte-identical to the verified convert_kernel.
// Ranges: X:4096 | Wqkv:6144 | bqkv:3 | Wo:2048 | bo:1  -> 12292 blocks.
// ---------------------------------------------------------------------------
__global__ __launch_bounds__(256) void convert_all_kernel(
    const void* __restrict__ X,    const void* __restrict__ Wqkv,
    const void* __restrict__ bqkv, const void* __restrict__ Wo,
    const void* __restrict__ bo,
    ushort_t* __restrict__ Xc,    ushort_t* __restrict__ Wqkvc,
    ushort_t* __restrict__ bqkvc, ushort_t* __restrict__ Woc,
    ushort_t* __restrict__ boc,   const int* __restrict__ flag)
{
    int blk = blockIdx.x;
    const void* src; ushort_t* dst; int n;
    if (blk < 4096)          { src = X;    dst = Xc;    n = 8388608; }
    else if (blk < 10240)    { blk -= 4096;  src = Wqkv; dst = Wqkvc; n = 12582912; }
    else if (blk < 10243)    { blk -= 10240; src = bqkv; dst = bqkvc; n = 6144; }
    else if (blk < 12291)    { blk -= 10243; src = Wo;   dst = Woc;   n = 4194304; }
    else                     { blk -= 12291; src = bo;   dst = boc;   n = 2048; }

    const int i0 = (blk * 256 + threadIdx.x) * 8;
    if (i0 + 8 > n) return;
    if (flag[0]) {
        const f32x4 a = *(const f32x4*)((const float*)src + i0);
        const f32x4 b = *(const f32x4*)((const float*)src + i0 + 4);
        ushort_t o[8];
        o[0]=f2bf(a[0]); o[1]=f2bf(a[1]); o[2]=f2bf(a[2]); o[3]=f2bf(a[3]);
        o[4]=f2bf(b[0]); o[5]=f2bf(b[1]); o[6]=f2bf(b[2]); o[7]=f2bf(b[3]);
        *(bf16x8*)(dst + i0) = *(const bf16x8*)o;
    } else {
        *(bf16x8*)(dst + i0) = *(const bf16x8*)((const ushort_t*)src + i0);
    }
}

// ---------------------------------------------------------------------------
// 256x256-tile 8-phase GEMM, C = A * B^T + bias (bf16 in/out).
// K-loop: round-0 verbatim. Epilogue: round-7 LDS-staged coalesced stores
// (verified: WRITE_SIZE 78->49MB).
// ---------------------------------------------------------------------------
__global__ __launch_bounds__(512, 2) void gemm256_bt_bias(
    const ushort_t* __restrict__ A, const ushort_t* __restrict__ B,
    const ushort_t* __restrict__ bias, ushort_t* __restrict__ C,
    int M, int N, int K)
{
    __shared__ __align__(16) ushort_t SM[65536];   // 4 slots x (8192 A + 8192 B) ushorts
    const int tid = threadIdx.x;
    const int l = tid & 63, ln = l & 15, q2 = l >> 4;
    const int w = tid >> 6, wm = w >> 2, wn = w & 3;
    const int m0 = blockIdx.y * 256, n0 = blockIdx.x * 256;
    const int NT = K >> 6;

#define STG_A256(slot, kbase, o) do { \
    const int s_ = (o) * 512 + tid; const int r_ = s_ >> 2; \
    const int q_ = (s_ & 3) ^ ((r_ >> 1) & 3); \
    gl2lds16(A + (size_t)(m0 + r_) * K + (kbase) + q_ * 8, \
             SM + (slot) * 16384 + s_ * 8); } while (0)
#define STG_B256(slot, kbase, o) do { \
    const int s_ = (o) * 512 + tid; const int r_ = s_ >> 2; \
    const int q_ = (s_ & 3) ^ ((r_ >> 1) & 3); \
    gl2lds16(B + (size_t)(n0 + r_) * K + (kbase) + q_ * 8, \
             SM + (slot) * 16384 + 8192 + s_ * 8); } while (0)
#define DSA256(slot, row) (*(const bf16x8*)(SM + (slot) * 16384 + (row) * 32 + ((q2 ^ (((row) >> 1) & 3)) << 3)))
#define DSB256(slot, row) (*(const bf16x8*)(SM + (slot) * 16384 + 8192 + (row) * 32 + ((q2 ^ (((row) >> 1) & 3)) << 3)))
#define BAR256() asm volatile("s_barrier" ::: "memory")

    f32x4 acc[8][4];
    const f32x4 z4 = {0.f, 0.f, 0.f, 0.f};
#pragma unroll
    for (int i = 0; i < 8; i++)
#pragma unroll
        for (int j = 0; j < 4; j++) acc[i][j] = z4;

    STG_A256(0, 0, 0);  STG_A256(0, 0, 1);  STG_B256(0, 0, 0);  STG_B256(0, 0, 1);
    STG_A256(1, 32, 0); STG_A256(1, 32, 1); STG_B256(1, 32, 0); STG_B256(1, 32, 1);
    if (NT > 1) STG_A256(2, 64, 0);
    asm volatile("s_waitcnt vmcnt(5)" ::: "memory");
    BAR256();

    for (int t = 0; t < NT; ++t) {
        const int s0 = (2 * t) & 3, s1 = (2 * t + 1) & 3;
        const int sA = (2 * t + 2) & 3, sB = (2 * t + 3) & 3;
        const int kA = (t + 1) << 6, kB = kA + 32, kC = (t + 2) << 6;
        const bool stAB = (t < NT - 1), stC = (t < NT - 2);
        const int rA0 = wm * 128, rA1 = wm * 128 + 64, rB = wn * 64;
        bf16x8 a0[4], a1[4], b00[2], b01[2], b10[2], b11[2];

        // ---- p0
#pragma unroll
        for (int ii = 0; ii < 4; ii++) a0[ii] = DSA256(s0, rA0 + ii * 16 + ln);
        b00[0] = DSB256(s0, rB + ln);
        b00[1] = DSB256(s0, rB + 16 + ln);
        if (stAB) STG_A256(sA, kA, 1);
        __builtin_amdgcn_s_setprio(1);
#pragma unroll
        for (int ii = 0; ii < 4; ii++) {
            acc[ii][0] = MFMA16(a0[ii], b00[0], acc[ii][0]);
            acc[ii][1] = MFMA16(a0[ii], b00[1], acc[ii][1]);
        }
        __builtin_amdgcn_s_setprio(0);
        if (stAB) { asm volatile("s_waitcnt vmcnt(2)" ::: "memory"); }
        else      { asm volatile("s_waitcnt vmcnt(0)" ::: "memory"); }
        BAR256();

        // ---- p1
#pragma unroll
        for (int ii = 0; ii < 4; ii++) a1[ii] = DSA256(s1, rA0 + ii * 16 + ln);
        b01[0] = DSB256(s1, rB + ln);
        b01[1] = DSB256(s1, rB + 16 + ln);
        if (stAB) STG_B256(sA, kA, 0);
        __builtin_amdgcn_s_setprio(1);
#pragma unroll
        for (int ii = 0; ii < 4; ii++) {
            acc[ii][0] = MFMA16(a1[ii], b01[0], acc[ii][0]);
            acc[ii][1] = MFMA16(a1[ii], b01[1], acc[ii][1]);
        }
        __builtin_amdgcn_s_setprio(0);
        BAR256();

        // ---- p2
        b10[0] = DSB256(s0, rB + 32 + ln);
        b10[1] = DSB256(s0, rB + 48 + ln);
        if (stAB) STG_B256(sA, kA, 1);
        __builtin_amdgcn_s_setprio(1);
#pragma unroll
        for (int ii = 0; ii < 4; ii++) {
            acc[ii][2] = MFMA16(a0[ii], b10[0], acc[ii][2]);
            acc[ii][3] = MFMA16(a0[ii], b10[1], acc[ii][3]);
        }
        __builtin_amdgcn_s_setprio(0);
        BAR256();

        // ---- p3
        b11[0] = DSB256(s1, rB + 32 + ln);
        b11[1] = DSB256(s1, rB + 48 + ln);
        if (stAB) STG_A256(sB, kB, 0);
        __builtin_amdgcn_s_setprio(1);
#pragma unroll
        for (int ii = 0; ii < 4; ii++) {
            acc[ii][2] = MFMA16(a1[ii], b11[0], acc[ii][2]);
            acc[ii][3] = MFMA16(a1[ii], b11[1], acc[ii][3]);
        }
        __builtin_amdgcn_s_setprio(0);
        BAR256();

        // ---- p4
#pragma unroll
        for (int ii = 0; ii < 4; ii++) a0[ii] = DSA256(s0, rA1 + ii * 16 + ln);
        if (stAB) STG_A256(sB, kB, 1);
        __builtin_amdgcn_s_setprio(1);
#pragma unroll
        for (int ii = 0; ii < 4; ii++) {
            acc[4 + ii][2] = MFMA16(a0[ii], b10[0], acc[4 + ii][2]);
            acc[4 + ii][3] = MFMA16(a0[ii], b10[1], acc[4 + ii][3]);
        }
        __builtin_amdgcn_s_setprio(0);
        BAR256();

        // ---- p5
#pragma unroll
        for (int ii = 0; ii < 4; ii++) a1[ii] = DSA256(s1, rA1 + ii * 16 + ln);
        if (stAB) STG_B256(sB, kB, 0);
        __builtin_amdgcn_s_setprio(1);
#pragma unroll
        for (int ii = 0; ii < 4; ii++) {
            acc[4 + ii][2] = MFMA16(a1[ii], b11[0], acc[4 + ii][2]);
            acc[4 + ii][3] = MFMA16(a1[ii], b11[1], acc[4 + ii][3]);
        }
        __builtin_amdgcn_s_setprio(0);
        BAR256();

        // ---- p6
        if (stAB) STG_B256(sB, kB, 1);
        __builtin_amdgcn_s_setprio(1);
#pragma unroll
        for (int ii = 0; ii < 4; ii++) {
            acc[4 + ii][0] = MFMA16(a0[ii], b00[0], acc[4 + ii][0]);
            acc[4 + ii][1] = MFMA16(a0[ii], b00[1], acc[4 + ii][1]);
        }
        __builtin_amdgcn_s_setprio(0);
        BAR256();

        // ---- p7
        if (stC) STG_A256(s0, kC, 0);
        __builtin_amdgcn_s_setprio(1);
#pragma unroll
        for (int ii = 0; ii < 4; ii++) {
            acc[4 + ii][0] = MFMA16(a1[ii], b01[0], acc[4 + ii][0]);
            acc[4 + ii][1] = MFMA16(a1[ii], b01[1], acc[4 + ii][1]);
        }
        __builtin_amdgcn_s_setprio(0);
        if (t < NT - 2)       { asm volatile("s_waitcnt vmcnt(5)" ::: "memory"); }
        else if (t == NT - 2) { asm volatile("s_waitcnt vmcnt(4)" ::: "memory"); }
        BAR256();
    }

    // ---- epilogue: LDS transpose-stage -> coalesced b128 stores (round-7).
    __syncthreads();   // K-loop LDS fully dead before overlay
#pragma unroll
    for (int j = 0; j < 4; j++) {
        const int nloc = wn * 64 + j * 16 + ln;
        const float bv = bf2f(bias[n0 + nloc]);
#pragma unroll
        for (int i = 0; i < 8; i++) {
            const int rloc = wm * 128 + i * 16 + q2 * 4;
#pragma unroll
            for (int r = 0; r < 4; r++)
                SM[(rloc + r) * 256 + nloc] = f2bf(acc[i][j][r] + bv);
        }
    }
    __syncthreads();
#pragma unroll
    for (int k = 0; k < 16; k++) {
        const int e = k * 512 + tid;
        const int row = e >> 5, unit = e & 31;
        *(bf16x8*)(C + (size_t)(m0 + row) * N + n0 + unit * 8) =
            *(const bf16x8*)(SM + row * 256 + unit * 8);
    }
#undef STG_A256
#undef STG_B256
#undef DSA256
#undef DSB256
#undef BAR256
}

// ---------------------------------------------------------------------------
// Final GEMM: fp32 output when flag=1 (verified), bf16 otherwise. (m97-style)
// Round-7 XCD-chunked block remap (verified).
// ---------------------------------------------------------------------------
__global__ __launch_bounds__(256) void gemm_bt_bias_out(
    const ushort_t* __restrict__ A, const ushort_t* __restrict__ B,
    const ushort_t* __restrict__ bias, void* __restrict__ C,
    int M, int N, int K, const int* __restrict__ flag)
{
    __shared__ __align__(16) ushort_t As[128 * 32];
    __shared__ __align__(16) ushort_t Bs[128 * 32];
    const int tid = threadIdx.x;
    const int w = tid >> 6, l = tid & 63, q = l >> 4, ln = l & 15;
    const int wm = w >> 1, wn = w & 1;
    const int lin = blockIdx.y * 16 + blockIdx.x;   // gridDim.x == 16
    const int nlin = (lin & 7) * 64 + (lin >> 3);
    const int m0 = (nlin >> 4) * 128, n0 = (nlin & 15) * 128;
    const int sr = tid >> 2;
    const int sc = (tid & 3) * 8;

    f32x4 acc[4][4];
    const f32x4 z4 = {0.f, 0.f, 0.f, 0.f};
    for (int i = 0; i < 4; i++) for (int j = 0; j < 4; j++) acc[i][j] = z4;

    for (int k0 = 0; k0 < K; k0 += 32) {
        __syncthreads();
        gl2lds16(A + (size_t)(m0 + sr) * K + k0 + sc,       As + sr * 32 + sc);
        gl2lds16(A + (size_t)(m0 + 64 + sr) * K + k0 + sc,  As + (64 + sr) * 32 + sc);
        gl2lds16(B + (size_t)(n0 + sr) * K + k0 + sc,       Bs + sr * 32 + sc);
        gl2lds16(B + (size_t)(n0 + 64 + sr) * K + k0 + sc,  Bs + (64 + sr) * 32 + sc);
        __syncthreads();
        bf16x8 a[4], bb[4];
        for (int i = 0; i < 4; i++)
            a[i]  = *(const bf16x8*)(As + (wm * 64 + i * 16 + ln) * 32 + q * 8);
        for (int j = 0; j < 4; j++)
            bb[j] = *(const bf16x8*)(Bs + (wn * 64 + j * 16 + ln) * 32 + q * 8);
        for (int i = 0; i < 4; i++)
            for (int j = 0; j < 4; j++)
                acc[i][j] = MFMA16(a[i], bb[j], acc[i][j]);
    }
    const int f = flag[0];
    for (int j = 0; j < 4; j++) {
        const int n = n0 + wn * 64 + j * 16 + ln;
        const float bv = bf2f(bias[n]);
        for (int i = 0; i < 4; i++) {
            const int mrow = m0 + wm * 64 + i * 16 + q * 4;
            for (int r = 0; r < 4; r++) {
                const float val = acc[i][j][r] + bv;
                const size_t idx = (size_t)(mrow + r) * N + n;
                if (f) ((float*)C)[idx] = val;
                else   ((ushort_t*)C)[idx] = f2bf(val);
            }
        }
    }
}

// ---------------------------------------------------------------------------
// ROUND-8: rope + vtrans fused (disjoint qkv regions: rope touches Q,K =
// [0,4096) of each row; vtrans reads V = [4096,6144) -> no ordering hazard).
// rope's cos/sin table is now computed per-block in LDS (64 sincosf across
// lanes 0-63, bit-identical expressions to the verified table kernel) --
// eliminates rope_table_kernel + the global table entirely.
// Blocks 0..4095 = rope; 4096..5119 = vtrans (round-5 vectorized, verified).
// ---------------------------------------------------------------------------
__global__ __launch_bounds__(256) void rope_vtrans_kernel(ushort_t* qkv,
                                                          ushort_t* __restrict__ Vt)
{
    __shared__ __align__(16) ushort_t lds[64 * 136];   // vtrans tile; rope uses 512B as f32 table
    const int t = threadIdx.x;

    if (blockIdx.x < 4096) {
        // ---- RoPE (table in LDS) ----
        const int bs = blockIdx.x;
        const int s = bs & 2047;
        const int qk = t >> 7;              // 0 = Q, 1 = K
        const int u = t & 127;
        const int h = u >> 3, i = u & 7;
        ushort_t* row = qkv + (size_t)bs * 6144 + qk * 2048 + h * 128;

        union { bf16x8 v; ushort_t e[8]; } L0, L1, L2, L3;
        L0.v = *(const bf16x8*)(row + 8 * i);
        L1.v = *(const bf16x8*)(row + 64 + 8 * i);
        L2.v = *(const bf16x8*)(row + 16 * i);
        L3.v = *(const bf16x8*)(row + 16 * i + 8);

        float* cs = (float*)lds;            // 128 floats = 512 B
        if (t < 64) {
            const float ang = powf(10000.0f, -(float)(2 * t) / 2048.0f);
            float sv, cv;
            sincosf((float)s * ang, &sv, &cv);
            cs[2 * t]     = cv;
            cs[2 * t + 1] = sv;
        }
        __syncthreads();   // table ready AND all threads' loads complete (vmcnt drain)

        float ca[4], sa_[4], cb[4], sb[4];
#pragma unroll
        for (int e = 0; e < 4; e++) {
            ca[e]  = cs[(4 * i + e) * 2];
            sa_[e] = cs[(4 * i + e) * 2 + 1];
            cb[e]  = cs[(32 + 4 * i + e) * 2];
            sb[e]  = cs[(32 + 4 * i + e) * 2 + 1];
        }
        ushort_t oA[8], oB[8];
#pragma unroll
        for (int d = 0; d < 8; d++) {
            const int e = d >> 1;
            const float pA = (d < 4) ? bf2f(L2.e[2 * d + 1]) : bf2f(L3.e[2 * d - 7]);
            const float pB = (d < 4) ? bf2f(L2.e[2 * d])     : bf2f(L3.e[2 * d - 8]);
            oA[d] = f2bf(ca[e] * bf2f(L0.e[d]) - sa_[e] * pA);
            oB[d] = f2bf(cb[e] * bf2f(L1.e[d]) + sb[e] * pB);
        }
        *(bf16x8*)(row + 8 * i)      = *(const bf16x8*)oA;
        *(bf16x8*)(row + 64 + 8 * i) = *(const bf16x8*)oB;
    } else {
        // ---- Vt[b,h,d,s] = qkv[b,s,2,h,d] ----
        const int blk = blockIdx.x - 4096;
        const int st = blk & 31, h = (blk >> 5) & 15, b = blk >> 9;
#pragma unroll
        for (int i = 0; i < 4; i++) {
            const int e = i * 256 + t;
            const int r = e >> 4, cb2 = e & 15;
            *(bf16x8*)(lds + r * 136 + cb2 * 8) =
                *(const bf16x8*)(qkv + (size_t)(b * 2048 + st * 64 + r) * 6144 + 4096 + h * 128 + cb2 * 8);
        }
        __syncthreads();
        const int d = t >> 1, s0 = (t & 1) * 32;
        const size_t obase = ((size_t)(b * 16 + h) * 128 + d) * 2048 + st * 64 + s0;
#pragma unroll
        for (int q4 = 0; q4 < 4; q4++) {
            ushort_t tmp[8];
#pragma unroll
            for (int j = 0; j < 8; j++) tmp[j] = lds[(s0 + q4 * 8 + j) * 136 + d];
            *(bf16x8*)(Vt + obase + q4 * 8) = *(const bf16x8*)tmp;
        }
    }
}

// ---------------------------------------------------------------------------
// Flash attention v3 (round-6/7, verified): swizzled Ks/Vs, T14 async-STAGE,
// T12 in-register P, T13 defer-max, setprio, XCD-aware 1-D grid.
// ---------------------------------------------------------------------------
__global__ __launch_bounds__(256, 2) void flash_kernel(
    const ushort_t* __restrict__ qkv, const ushort_t* __restrict__ Vt,
    const int* __restrict__ mask, ushort_t* __restrict__ AO)
{
    __shared__ __align__(16) ushort_t SM[16384];   // 32 KiB
    ushort_t* Ks = SM;          // [64][128] bf16, 16B-unit swizzle ^(row&15)
    ushort_t* Vs = SM + 8192;   // [128][64] bf16, 16B-unit swizzle ^(row&7)
    const int t = threadIdx.x;
    const int w = t >> 6, l = t & 63, lq = l & 31, q2 = l >> 5;
    const int bid = blockIdx.x;
    const int xcd = bid & 7, ii = bid >> 3;
    const int p = xcd * 4 + (ii >> 4);
    const int qb = (ii & 15) * 128;
    const int h = p & 15, b = p >> 4;
    const size_t brow = (size_t)b * 2048;
    const float scale = 0.08838834764831845f;   // 1/sqrt(128)
    const int qrow = qb + w * 32 + lq;
    const size_t vbase = (size_t)(b * 16 + h) * 128;

    bf16x8 qf[8];
#pragma unroll
    for (int kb = 0; kb < 8; kb++)
        qf[kb] = *(const bf16x8*)(qkv + (brow + qrow) * 6144 + h * 128 + kb * 16 + q2 * 8);

    float m_old = -1e30f, lsum = 0.f;
    f32x16 acc_o[4];
#pragma unroll
    for (int dt = 0; dt < 4; dt++)
#pragma unroll
        for (int r = 0; r < 16; r++) acc_o[dt][r] = 0.f;

    bf16x8 kst[4], vst[4];
#pragma unroll
    for (int i = 0; i < 4; i++) {
        const int s_ = i * 256 + t; const int row = s_ >> 4; const int u = s_ & 15;
        kst[i] = *(const bf16x8*)(qkv + (brow + row) * 6144 + 2048 + h * 128 + u * 8);
    }
#pragma unroll
    for (int i = 0; i < 4; i++) {
        const int s_ = i * 256 + t; const int row = s_ >> 3; const int u = s_ & 7;
        vst[i] = *(const bf16x8*)(Vt + (vbase + row) * 2048 + u * 8);
    }

    for (int s0 = 0; s0 < 2048; s0 += 64) {
        const int mk = mask[brow + s0 + l];
        const unsigned long long bm = __ballot(mk != 0);
        asm volatile("s_waitcnt lgkmcnt(0)" ::: "memory");
        asm volatile("s_barrier" ::: "memory");          // all waves done reading prev tile
#pragma unroll
        for (int i = 0; i < 4; i++) {
            const int s_ = i * 256 + t; const int row = s_ >> 4; const int u = s_ & 15;
            *(bf16x8*)(Ks + row * 128 + ((u ^ (row & 15)) << 3)) = kst[i];
        }
#pragma unroll
        for (int i = 0; i < 4; i++) {
            const int s_ = i * 256 + t; const int row = s_ >> 3; const int u = s_ & 7;
            *(bf16x8*)(Vs + row * 64 + ((u ^ (row & 7)) << 3)) = vst[i];
        }
        if (s0 + 64 < 2048) {
#pragma unroll
            for (int i = 0; i < 4; i++) {
                const int s_ = i * 256 + t; const int row = s_ >> 4; const int u = s_ & 15;
                kst[i] = *(const bf16x8*)(qkv + (brow + s0 + 64 + row) * 6144 + 2048 + h * 128 + u * 8);
            }
#pragma unroll
            for (int i = 0; i < 4; i++) {
                const int s_ = i * 256 + t; const int row = s_ >> 3; const int u = s_ & 7;
                vst[i] = *(const bf16x8*)(Vt + (vbase + row) * 2048 + s0 + 64 + u * 8);
            }
        }
        asm volatile("s_waitcnt lgkmcnt(0)" ::: "memory");  // ds_writes drained (NOT vmcnt)
        asm volatile("s_barrier" ::: "memory");             // writes visible

        f32x16 sa[2];
#pragma unroll
        for (int mt = 0; mt < 2; mt++) {
#pragma unroll
            for (int r = 0; r < 16; r++) sa[mt][r] = 0.f;
            const int row = mt * 32 + lq;
            __builtin_amdgcn_s_setprio(1);
#pragma unroll
            for (int kb = 0; kb < 8; kb++) {
                bf16x8 a = *(const bf16x8*)(Ks + row * 128 + (((kb * 2 + q2) ^ (row & 15)) << 3));
                sa[mt] = MFMA32(a, qf[kb], sa[mt]);
            }
            __builtin_amdgcn_s_setprio(0);
        }
        float p_[32];
        float mr = -1e30f;
        if (bm == ~0ull) {
#pragma unroll
            for (int mt = 0; mt < 2; mt++)
#pragma unroll
                for (int r = 0; r < 16; r++) {
                    const float v = sa[mt][r] * scale;
                    p_[mt * 16 + r] = v;
                    mr = fmaxf(mr, v);
                }
        } else {
#pragma unroll
            for (int mt = 0; mt < 2; mt++)
#pragma unroll
                for (int r = 0; r < 16; r++) {
                    const int srow = mt * 32 + (r & 3) + 8 * (r >> 2) + 4 * q2;
                    const float bias = ((bm >> srow) & 1ull) ? 0.f : -1e9f;
                    const float v = sa[mt][r] * scale + bias;
                    p_[mt * 16 + r] = v;
                    mr = fmaxf(mr, v);
                }
        }
        mr = fmaxf(mr, __shfl_xor(mr, 32, 64));
        if (!__all(mr <= m_old + 8.0f)) {        // T13 defer-max
            const float mnew = fmaxf(m_old, mr);
            const float alpha = __expf(m_old - mnew);
            lsum *= alpha;
#pragma unroll
            for (int dt = 0; dt < 4; dt++)
#pragma unroll
                for (int r = 0; r < 16; r++) acc_o[dt][r] *= alpha;
            m_old = mnew;
        }
        float rs = 0.f;
#pragma unroll
        for (int i = 0; i < 32; i++) { p_[i] = __expf(p_[i] - m_old); rs += p_[i]; }
        rs += __shfl_xor(rs, 32, 64);
        lsum += rs;

#pragma unroll
        for (int kb = 0; kb < 4; kb++) {
            const int bb = (kb >> 1) * 16 + (kb & 1) * 8;
            unsigned w01, w23, w45, w67;
            asm("v_cvt_pk_bf16_f32 %0, %1, %2" : "=v"(w01) : "v"(p_[bb + 0]), "v"(p_[bb + 1]));
            asm("v_cvt_pk_bf16_f32 %0, %1, %2" : "=v"(w23) : "v"(p_[bb + 2]), "v"(p_[bb + 3]));
            asm("v_cvt_pk_bf16_f32 %0, %1, %2" : "=v"(w45) : "v"(p_[bb + 4]), "v"(p_[bb + 5]));
            asm("v_cvt_pk_bf16_f32 %0, %1, %2" : "=v"(w67) : "v"(p_[bb + 6]), "v"(p_[bb + 7]));
            asm("v_permlane32_swap_b32 %0, %1" : "+v"(w01), "+v"(w45));
            asm("v_permlane32_swap_b32 %0, %1" : "+v"(w23), "+v"(w67));
            union { unsigned u[4]; bf16x8 v8; } pu;
            pu.u[0] = w01; pu.u[1] = w23; pu.u[2] = w45; pu.u[3] = w67;
            __builtin_amdgcn_s_setprio(1);
#pragma unroll
            for (int dt = 0; dt < 4; dt++) {
                const int row = dt * 32 + lq;
                bf16x8 va = *(const bf16x8*)(Vs + row * 64 + (((kb * 2 + q2) ^ (row & 7)) << 3));
                acc_o[dt] = MFMA32(va, pu.v8, acc_o[dt]);
            }
            __builtin_amdgcn_s_setprio(0);
        }
    }
    __syncthreads();   // all PV reads done before epilogue overlays SM
    const float inv = (lsum > 0.f) ? 1.0f / lsum : 0.f;
#pragma unroll
    for (int dt = 0; dt < 4; dt++)
#pragma unroll
        for (int r2 = 0; r2 < 4; r2++) {
            us4 ov;
#pragma unroll
            for (int j = 0; j < 4; j++) ov[j] = f2bf(acc_o[dt][r2 * 4 + j] * inv);
            const int row = w * 32 + lq;
            const int unit = dt * 4 + r2;
            *(us4*)(SM + row * 128 + ((unit ^ (row & 15)) << 3) + q2 * 4) = ov;
        }
    __syncthreads();
#pragma unroll
    for (int i = 0; i < 8; i++) {
        const int rl = i * 4 + (l >> 4), ch = l & 15;
        const int row = w * 32 + rl;
        bf16x8 vv = *(const bf16x8*)(SM + row * 128 + ((ch ^ (row & 15)) << 3));
        *(bf16x8*)(AO + (brow + qb + row) * 2048 + h * 128 + ch * 8) = vv;
    }
}

extern "C" void kernel_launch(void* const* d_in, const int* in_sizes, int n_in,
                              void* d_out, int out_size, void* d_ws, size_t ws_size,
                              hipStream_t stream)
{
    (void)in_sizes; (void)n_in; (void)out_size; (void)ws_size;
    const void* X    = d_in[0];
    const int*  mask = (const int*)d_in[1];
    const void* Wqkv = d_in[2];
    const void* bqkv = d_in[3];
    const void* Wo   = d_in[4];
    const void* bo   = d_in[5];

    int*      flag  = (int*)d_ws;
    ushort_t* Xc    = (ushort_t*)d_ws + 16;
    ushort_t* Wqkvc = Xc + 8388608;
    ushort_t* bqkvc = Wqkvc + 12582912;
    ushort_t* Woc   = bqkvc + 6144;
    ushort_t* boc   = Woc + 4194304;
    ushort_t* qkv   = boc + 2048;
    ushort_t* Vt    = Wqkvc;   // reuse: Wqkv dead after gemm1 (Vt = 8.39M ushorts)
    ushort_t* AO    = Xc;      // reuse: X dead after gemm1

    detect_kernel<<<1, 256, 0, stream>>>((const ushort_t*)Wqkv, flag);
    convert_all_kernel<<<12292, 256, 0, stream>>>(X, Wqkv, bqkv, Wo, bo,
                                                  Xc, Wqkvc, bqkvc, Woc, boc, flag);
    gemm256_bt_bias<<<dim3(6144 / 256, 4096 / 256), 512, 0, stream>>>(Xc, Wqkvc, bqkvc, qkv, 4096, 6144, 2048);
    rope_vtrans_kernel<<<5120, 256, 0, stream>>>(qkv, Vt);
    flash_kernel<<<512, 256, 0, stream>>>(qkv, Vt, mask, AO);
    gemm_bt_bias_out<<<dim3(2048 / 128, 4096 / 128), 256, 0, stream>>>(AO, Woc, boc, d_out, 4096, 2048, 2048, flag);
}

// Round 10
// 525.465 us; speedup vs baseline: 1.1731x; 1.0053x over previous
//
#include <hip/hip_runtime.h>
#include <hip/hip_bf16.h>
#include <math.h>

typedef __bf16 bf16x8 __attribute__((ext_vector_type(8)));
typedef float  f32x4  __attribute__((ext_vector_type(4)));
typedef float  f32x16 __attribute__((ext_vector_type(16)));
typedef unsigned short ushort_t;
typedef ushort_t us4 __attribute__((ext_vector_type(4)));

#define MFMA16(a, b, c) __builtin_amdgcn_mfma_f32_16x16x32_bf16((a), (b), (c), 0, 0, 0)
#define MFMA32(a, b, c) __builtin_amdgcn_mfma_f32_32x32x16_bf16((a), (b), (c), 0, 0, 0)

__device__ __forceinline__ float bf2f(ushort_t h) {
    union { unsigned u; float f; } v; v.u = ((unsigned)h) << 16; return v.f;
}
__device__ __forceinline__ ushort_t f2bf(float x) {
    union { float f; unsigned u; } v; v.f = x;
    unsigned r = v.u + 0x7FFFu + ((v.u >> 16) & 1u);
    return (ushort_t)(r >> 16);
}
// async global->LDS, 16B per lane. LDS dest must be wave-uniform base + lane*16.
__device__ __forceinline__ void gl2lds16(const void* g, void* l) {
    __builtin_amdgcn_global_load_lds((__attribute__((address_space(1))) void*)(g),
                                     (__attribute__((address_space(3))) void*)(l),
                                     16, 0, 0);
}

// ---------------------------------------------------------------------------
// Dtype detector (verified: flag=1 fires, inputs are fp32).
// ---------------------------------------------------------------------------
__global__ __launch_bounds__(256) void detect_kernel(const ushort_t* __restrict__ w, int* flag)
{
    __shared__ int cnt[256];
    const int t = threadIdx.x;
    int c = 0;
    for (int i = t; i < 65536; i += 256) {
        const unsigned hw = w[i];
        const unsigned e = (hw >> 7) & 0xFFu;
        if (e == 0xFFu || (e == 0u && (hw & 0x7Fu) != 0u)) c++;
    }
    cnt[t] = c;
    __syncthreads();
    for (int s = 128; s > 0; s >>= 1) {
        if (t < s) cnt[t] += cnt[t + s];
        __syncthreads();
    }
    if (t == 0) flag[0] = (cnt[0] >= 8) ? 1 : 0;
}

// ---------------------------------------------------------------------------
// All 5 dtype-convert launches fused (round-8, verified).
// Ranges: X:4096 | Wqkv:6144 | bqkv:3 | Wo:2048 | bo:1  -> 12292 blocks.
// ---------------------------------------------------------------------------
__global__ __launch_bounds__(256) void convert_all_kernel(
    const void* __restrict__ X,    const void* __restrict__ Wqkv,
    const void* __restrict__ bqkv, const void* __restrict__ Wo,
    const void* __restrict__ bo,
    ushort_t* __restrict__ Xc,    ushort_t* __restrict__ Wqkvc,
    ushort_t* __restrict__ bqkvc, ushort_t* __restrict__ Woc,
    ushort_t* __restrict__ boc,   const int* __restrict__ flag)
{
    int blk = blockIdx.x;
    const void* src; ushort_t* dst; int n;
    if (blk < 4096)          { src = X;    dst = Xc;    n = 8388608; }
    else if (blk < 10240)    { blk -= 4096;  src = Wqkv; dst = Wqkvc; n = 12582912; }
    else if (blk < 10243)    { blk -= 10240; src = bqkv; dst = bqkvc; n = 6144; }
    else if (blk < 12291)    { blk -= 10243; src = Wo;   dst = Woc;   n = 4194304; }
    else                     { blk -= 12291; src = bo;   dst = boc;   n = 2048; }

    const int i0 = (blk * 256 + threadIdx.x) * 8;
    if (i0 + 8 > n) return;
    if (flag[0]) {
        const f32x4 a = *(const f32x4*)((const float*)src + i0);
        const f32x4 b = *(const f32x4*)((const float*)src + i0 + 4);
        ushort_t o[8];
        o[0]=f2bf(a[0]); o[1]=f2bf(a[1]); o[2]=f2bf(a[2]); o[3]=f2bf(a[3]);
        o[4]=f2bf(b[0]); o[5]=f2bf(b[1]); o[6]=f2bf(b[2]); o[7]=f2bf(b[3]);
        *(bf16x8*)(dst + i0) = *(const bf16x8*)o;
    } else {
        *(bf16x8*)(dst + i0) = *(const bf16x8*)((const ushort_t*)src + i0);
    }
}

// ---------------------------------------------------------------------------
// Shared 256x256-tile 8-phase K-loop (round-0 verbatim, verified).
// acc layout on return: acc[i][j][r] = C[m0 + wm*128 + i*16 + q2*4 + r]
//                                       [n0 + wn*64 + j*16 + ln]
// ---------------------------------------------------------------------------
#define STG_A256(slot, kbase, o) do { \
    const int s_ = (o) * 512 + tid; const int r_ = s_ >> 2; \
    const int q_ = (s_ & 3) ^ ((r_ >> 1) & 3); \
    gl2lds16(A + (size_t)(m0 + r_) * K + (kbase) + q_ * 8, \
             SM + (slot) * 16384 + s_ * 8); } while (0)
#define STG_B256(slot, kbase, o) do { \
    const int s_ = (o) * 512 + tid; const int r_ = s_ >> 2; \
    const int q_ = (s_ & 3) ^ ((r_ >> 1) & 3); \
    gl2lds16(B + (size_t)(n0 + r_) * K + (kbase) + q_ * 8, \
             SM + (slot) * 16384 + 8192 + s_ * 8); } while (0)
#define DSA256(slot, row) (*(const bf16x8*)(SM + (slot) * 16384 + (row) * 32 + ((q2 ^ (((row) >> 1) & 3)) << 3)))
#define DSB256(slot, row) (*(const bf16x8*)(SM + (slot) * 16384 + 8192 + (row) * 32 + ((q2 ^ (((row) >> 1) & 3)) << 3)))
#define BAR256() asm volatile("s_barrier" ::: "memory")

#define GEMM256_KLOOP() \
    STG_A256(0, 0, 0);  STG_A256(0, 0, 1);  STG_B256(0, 0, 0);  STG_B256(0, 0, 1); \
    STG_A256(1, 32, 0); STG_A256(1, 32, 1); STG_B256(1, 32, 0); STG_B256(1, 32, 1); \
    if (NT > 1) STG_A256(2, 64, 0); \
    asm volatile("s_waitcnt vmcnt(5)" ::: "memory"); \
    BAR256(); \
    for (int t = 0; t < NT; ++t) { \
        const int s0 = (2 * t) & 3, s1 = (2 * t + 1) & 3; \
        const int sA = (2 * t + 2) & 3, sB = (2 * t + 3) & 3; \
        const int kA = (t + 1) << 6, kB = kA + 32, kC = (t + 2) << 6; \
        const bool stAB = (t < NT - 1), stC = (t < NT - 2); \
        const int rA0 = wm * 128, rA1 = wm * 128 + 64, rB = wn * 64; \
        bf16x8 a0[4], a1[4], b00[2], b01[2], b10[2], b11[2]; \
        _Pragma("unroll") \
        for (int ii = 0; ii < 4; ii++) a0[ii] = DSA256(s0, rA0 + ii * 16 + ln); \
        b00[0] = DSB256(s0, rB + ln); \
        b00[1] = DSB256(s0, rB + 16 + ln); \
        if (stAB) STG_A256(sA, kA, 1); \
        __builtin_amdgcn_s_setprio(1); \
        _Pragma("unroll") \
        for (int ii = 0; ii < 4; ii++) { \
            acc[ii][0] = MFMA16(a0[ii], b00[0], acc[ii][0]); \
            acc[ii][1] = MFMA16(a0[ii], b00[1], acc[ii][1]); \
        } \
        __builtin_amdgcn_s_setprio(0); \
        if (stAB) { asm volatile("s_waitcnt vmcnt(2)" ::: "memory"); } \
        else      { asm volatile("s_waitcnt vmcnt(0)" ::: "memory"); } \
        BAR256(); \
        _Pragma("unroll") \
        for (int ii = 0; ii < 4; ii++) a1[ii] = DSA256(s1, rA0 + ii * 16 + ln); \
        b01[0] = DSB256(s1, rB + ln); \
        b01[1] = DSB256(s1, rB + 16 + ln); \
        if (stAB) STG_B256(sA, kA, 0); \
        __builtin_amdgcn_s_setprio(1); \
        _Pragma("unroll") \
        for (int ii = 0; ii < 4; ii++) { \
            acc[ii][0] = MFMA16(a1[ii], b01[0], acc[ii][0]); \
            acc[ii][1] = MFMA16(a1[ii], b01[1], acc[ii][1]); \
        } \
        __builtin_amdgcn_s_setprio(0); \
        BAR256(); \
        b10[0] = DSB256(s0, rB + 32 + ln); \
        b10[1] = DSB256(s0, rB + 48 + ln); \
        if (stAB) STG_B256(sA, kA, 1); \
        __builtin_amdgcn_s_setprio(1); \
        _Pragma("unroll") \
        for (int ii = 0; ii < 4; ii++) { \
            acc[ii][2] = MFMA16(a0[ii], b10[0], acc[ii][2]); \
            acc[ii][3] = MFMA16(a0[ii], b10[1], acc[ii][3]); \
        } \
        __builtin_amdgcn_s_setprio(0); \
        BAR256(); \
        b11[0] = DSB256(s1, rB + 32 + ln); \
        b11[1] = DSB256(s1, rB + 48 + ln); \
        if (stAB) STG_A256(sB, kB, 0); \
        __builtin_amdgcn_s_setprio(1); \
        _Pragma("unroll") \
        for (int ii = 0; ii < 4; ii++) { \
            acc[ii][2] = MFMA16(a1[ii], b11[0], acc[ii][2]); \
            acc[ii][3] = MFMA16(a1[ii], b11[1], acc[ii][3]); \
        } \
        __builtin_amdgcn_s_setprio(0); \
        BAR256(); \
        _Pragma("unroll") \
        for (int ii = 0; ii < 4; ii++) a0[ii] = DSA256(s0, rA1 + ii * 16 + ln); \
        if (stAB) STG_A256(sB, kB, 1); \
        __builtin_amdgcn_s_setprio(1); \
        _Pragma("unroll") \
        for (int ii = 0; ii < 4; ii++) { \
            acc[4 + ii][2] = MFMA16(a0[ii], b10[0], acc[4 + ii][2]); \
            acc[4 + ii][3] = MFMA16(a0[ii], b10[1], acc[4 + ii][3]); \
        } \
        __builtin_amdgcn_s_setprio(0); \
        BAR256(); \
        _Pragma("unroll") \
        for (int ii = 0; ii < 4; ii++) a1[ii] = DSA256(s1, rA1 + ii * 16 + ln); \
        if (stAB) STG_B256(sB, kB, 0); \
        __builtin_amdgcn_s_setprio(1); \
        _Pragma("unroll") \
        for (int ii = 0; ii < 4; ii++) { \
            acc[4 + ii][2] = MFMA16(a1[ii], b11[0], acc[4 + ii][2]); \
            acc[4 + ii][3] = MFMA16(a1[ii], b11[1], acc[4 + ii][3]); \
        } \
        __builtin_amdgcn_s_setprio(0); \
        BAR256(); \
        if (stAB) STG_B256(sB, kB, 1); \
        __builtin_amdgcn_s_setprio(1); \
        _Pragma("unroll") \
        for (int ii = 0; ii < 4; ii++) { \
            acc[4 + ii][0] = MFMA16(a0[ii], b00[0], acc[4 + ii][0]); \
            acc[4 + ii][1] = MFMA16(a0[ii], b00[1], acc[4 + ii][1]); \
        } \
        __builtin_amdgcn_s_setprio(0); \
        BAR256(); \
        if (stC) STG_A256(s0, kC, 0); \
        __builtin_amdgcn_s_setprio(1); \
        _Pragma("unroll") \
        for (int ii = 0; ii < 4; ii++) { \
            acc[4 + ii][0] = MFMA16(a1[ii], b01[0], acc[4 + ii][0]); \
            acc[4 + ii][1] = MFMA16(a1[ii], b01[1], acc[4 + ii][1]); \
        } \
        __builtin_amdgcn_s_setprio(0); \
        if (t < NT - 2)       { asm volatile("s_waitcnt vmcnt(5)" ::: "memory"); } \
        else if (t == NT - 2) { asm volatile("s_waitcnt vmcnt(4)" ::: "memory"); } \
        BAR256(); \
    }

// ---------------------------------------------------------------------------
// QKV GEMM: 256x256 8-phase + round-7 coalesced bf16 epilogue (verified).
// ---------------------------------------------------------------------------
__global__ __launch_bounds__(512, 2) void gemm256_bt_bias(
    const ushort_t* __restrict__ A, const ushort_t* __restrict__ B,
    const ushort_t* __restrict__ bias, ushort_t* __restrict__ C,
    int M, int N, int K)
{
    __shared__ __align__(16) ushort_t SM[65536];
    const int tid = threadIdx.x;
    const int l = tid & 63, ln = l & 15, q2 = l >> 4;
    const int w = tid >> 6, wm = w >> 2, wn = w & 3;
    const int m0 = blockIdx.y * 256, n0 = blockIdx.x * 256;
    const int NT = K >> 6;

    f32x4 acc[8][4];
    const f32x4 z4 = {0.f, 0.f, 0.f, 0.f};
#pragma unroll
    for (int i = 0; i < 8; i++)
#pragma unroll
        for (int j = 0; j < 4; j++) acc[i][j] = z4;

    GEMM256_KLOOP();

    // bf16 epilogue: LDS transpose-stage -> coalesced b128 stores (round-7).
    __syncthreads();
#pragma unroll
    for (int j = 0; j < 4; j++) {
        const int nloc = wn * 64 + j * 16 + ln;
        const float bv = bf2f(bias[n0 + nloc]);
#pragma unroll
        for (int i = 0; i < 8; i++) {
            const int rloc = wm * 128 + i * 16 + q2 * 4;
#pragma unroll
            for (int r = 0; r < 4; r++)
                SM[(rloc + r) * 256 + nloc] = f2bf(acc[i][j][r] + bv);
        }
    }
    __syncthreads();
#pragma unroll
    for (int k = 0; k < 16; k++) {
        const int e = k * 512 + tid;
        const int row = e >> 5, unit = e & 31;
        *(bf16x8*)(C + (size_t)(m0 + row) * N + n0 + unit * 8) =
            *(const bf16x8*)(SM + row * 256 + unit * 8);
    }
}

// ---------------------------------------------------------------------------
// ROUND-9: final GEMM upgraded to the SAME verified 256x256 8-phase K-loop
// (was m97 128^2 at ~240 TF -- weakest kernel in the pipeline). Grid (8,16) =
// 128 blocks; per-block time is a measured quantity (~97us/round on gemm256).
// Accumulation order is bit-identical to the old kernel (ascending k, one
// 16x16x32 MFMA per 32-chunk) -> absmax unchanged exactly.
// Epilogue: flag=0 -> bf16 path (verbatim round-7). flag=1 (fires in bench) ->
// fp32 2-pass LDS staging: pass p stages rows [128p,128p+128) as f32[128][256]
// = exactly 128KB; wm==p waves ds_write, then ALL threads store f32x4 in
// 1KB-per-wave contiguous runs (fixes old fp32 path's half-cacheline stores).
// ---------------------------------------------------------------------------
__global__ __launch_bounds__(512, 2) void gemm256_bt_bias_out(
    const ushort_t* __restrict__ A, const ushort_t* __restrict__ B,
    const ushort_t* __restrict__ bias, void* __restrict__ C,
    int M, int N, int K, const int* __restrict__ flag)
{
    __shared__ __align__(16) ushort_t SM[65536];
    const int tid = threadIdx.x;
    const int l = tid & 63, ln = l & 15, q2 = l >> 4;
    const int w = tid >> 6, wm = w >> 2, wn = w & 3;
    const int m0 = blockIdx.y * 256, n0 = blockIdx.x * 256;
    const int NT = K >> 6;

    f32x4 acc[8][4];
    const f32x4 z4 = {0.f, 0.f, 0.f, 0.f};
#pragma unroll
    for (int i = 0; i < 8; i++)
#pragma unroll
        for (int j = 0; j < 4; j++) acc[i][j] = z4;

    GEMM256_KLOOP();

    const int f = flag[0];
    __syncthreads();   // K-loop LDS dead before overlay
    if (f) {
        // fp32 output, 2-pass LDS staging (f32[128][256] per pass = 128KB)
        float* SMf = (float*)SM;
#pragma unroll
        for (int p = 0; p < 2; p++) {
            if (wm == p) {
#pragma unroll
                for (int j = 0; j < 4; j++) {
                    const int nloc = wn * 64 + j * 16 + ln;
                    const float bv = bf2f(bias[n0 + nloc]);
#pragma unroll
                    for (int i = 0; i < 8; i++) {
                        const int rloc = i * 16 + q2 * 4;   // 0..127 within pass
#pragma unroll
                        for (int r = 0; r < 4; r++)
                            SMf[(rloc + r) * 256 + nloc] = acc[i][j][r] + bv;
                    }
                }
            }
            __syncthreads();
#pragma unroll
            for (int k = 0; k < 16; k++) {
                const int e = k * 512 + tid;
                const int row = e >> 6, u = e & 63;
                *(f32x4*)((float*)C + (size_t)(m0 + p * 128 + row) * N + n0 + u * 4) =
                    *(const f32x4*)(SMf + row * 256 + u * 4);
            }
            if (p == 0) __syncthreads();   // stores of pass 0 read before pass 1 overwrites
        }
    } else {
        // bf16 output (round-7 verified path)
#pragma unroll
        for (int j = 0; j < 4; j++) {
            const int nloc = wn * 64 + j * 16 + ln;
            const float bv = bf2f(bias[n0 + nloc]);
#pragma unroll
            for (int i = 0; i < 8; i++) {
                const int rloc = wm * 128 + i * 16 + q2 * 4;
#pragma unroll
                for (int r = 0; r < 4; r++)
                    SM[(rloc + r) * 256 + nloc] = f2bf(acc[i][j][r] + bv);
            }
        }
        __syncthreads();
#pragma unroll
        for (int k = 0; k < 16; k++) {
            const int e = k * 512 + tid;
            const int row = e >> 5, unit = e & 31;
            *(bf16x8*)((ushort_t*)C + (size_t)(m0 + row) * N + n0 + unit * 8) =
                *(const bf16x8*)(SM + row * 256 + unit * 8);
        }
    }
}

// ---------------------------------------------------------------------------
// rope + vtrans fused (round-8, verified).
// ---------------------------------------------------------------------------
__global__ __launch_bounds__(256) void rope_vtrans_kernel(ushort_t* qkv,
                                                          ushort_t* __restrict__ Vt)
{
    __shared__ __align__(16) ushort_t lds[64 * 136];
    const int t = threadIdx.x;

    if (blockIdx.x < 4096) {
        const int bs = blockIdx.x;
        const int s = bs & 2047;
        const int qk = t >> 7;              // 0 = Q, 1 = K
        const int u = t & 127;
        const int h = u >> 3, i = u & 7;
        ushort_t* row = qkv + (size_t)bs * 6144 + qk * 2048 + h * 128;

        union { bf16x8 v; ushort_t e[8]; } L0, L1, L2, L3;
        L0.v = *(const bf16x8*)(row + 8 * i);
        L1.v = *(const bf16x8*)(row + 64 + 8 * i);
        L2.v = *(const bf16x8*)(row + 16 * i);
        L3.v = *(const bf16x8*)(row + 16 * i + 8);

        float* cs = (float*)lds;
        if (t < 64) {
            const float ang = powf(10000.0f, -(float)(2 * t) / 2048.0f);
            float sv, cv;
            sincosf((float)s * ang, &sv, &cv);
            cs[2 * t]     = cv;
            cs[2 * t + 1] = sv;
        }
        __syncthreads();

        float ca[4], sa_[4], cb[4], sb[4];
#pragma unroll
        for (int e = 0; e < 4; e++) {
            ca[e]  = cs[(4 * i + e) * 2];
            sa_[e] = cs[(4 * i + e) * 2 + 1];
            cb[e]  = cs[(32 + 4 * i + e) * 2];
            sb[e]  = cs[(32 + 4 * i + e) * 2 + 1];
        }
        ushort_t oA[8], oB[8];
#pragma unroll
        for (int d = 0; d < 8; d++) {
            const int e = d >> 1;
            const float pA = (d < 4) ? bf2f(L2.e[2 * d + 1]) : bf2f(L3.e[2 * d - 7]);
            const float pB = (d < 4) ? bf2f(L2.e[2 * d])     : bf2f(L3.e[2 * d - 8]);
            oA[d] = f2bf(ca[e] * bf2f(L0.e[d]) - sa_[e] * pA);
            oB[d] = f2bf(cb[e] * bf2f(L1.e[d]) + sb[e] * pB);
        }
        *(bf16x8*)(row + 8 * i)      = *(const bf16x8*)oA;
        *(bf16x8*)(row + 64 + 8 * i) = *(const bf16x8*)oB;
    } else {
        const int blk = blockIdx.x - 4096;
        const int st = blk & 31, h = (blk >> 5) & 15, b = blk >> 9;
#pragma unroll
        for (int i = 0; i < 4; i++) {
            const int e = i * 256 + t;
            const int r = e >> 4, cb2 = e & 15;
            *(bf16x8*)(lds + r * 136 + cb2 * 8) =
                *(const bf16x8*)(qkv + (size_t)(b * 2048 + st * 64 + r) * 6144 + 4096 + h * 128 + cb2 * 8);
        }
        __syncthreads();
        const int d = t >> 1, s0 = (t & 1) * 32;
        const size_t obase = ((size_t)(b * 16 + h) * 128 + d) * 2048 + st * 64 + s0;
#pragma unroll
        for (int q4 = 0; q4 < 4; q4++) {
            ushort_t tmp[8];
#pragma unroll
            for (int j = 0; j < 8; j++) tmp[j] = lds[(s0 + q4 * 8 + j) * 136 + d];
            *(bf16x8*)(Vt + obase + q4 * 8) = *(const bf16x8*)tmp;
        }
    }
}

// ---------------------------------------------------------------------------
// Flash attention v3 (round-6/7, verified): swizzled Ks/Vs, T14 async-STAGE,
// T12 in-register P, T13 defer-max, setprio, XCD-aware 1-D grid.
// ---------------------------------------------------------------------------
__global__ __launch_bounds__(256, 2) void flash_kernel(
    const ushort_t* __restrict__ qkv, const ushort_t* __restrict__ Vt,
    const int* __restrict__ mask, ushort_t* __restrict__ AO)
{
    __shared__ __align__(16) ushort_t SM[16384];   // 32 KiB
    ushort_t* Ks = SM;          // [64][128] bf16, 16B-unit swizzle ^(row&15)
    ushort_t* Vs = SM + 8192;   // [128][64] bf16, 16B-unit swizzle ^(row&7)
    const int t = threadIdx.x;
    const int w = t >> 6, l = t & 63, lq = l & 31, q2 = l >> 5;
    const int bid = blockIdx.x;
    const int xcd = bid & 7, ii = bid >> 3;
    const int p = xcd * 4 + (ii >> 4);
    const int qb = (ii & 15) * 128;
    const int h = p & 15, b = p >> 4;
    const size_t brow = (size_t)b * 2048;
    const float scale = 0.08838834764831845f;   // 1/sqrt(128)
    const int qrow = qb + w * 32 + lq;
    const size_t vbase = (size_t)(b * 16 + h) * 128;

    bf16x8 qf[8];
#pragma unroll
    for (int kb = 0; kb < 8; kb++)
        qf[kb] = *(const bf16x8*)(qkv + (brow + qrow) * 6144 + h * 128 + kb * 16 + q2 * 8);

    float m_old = -1e30f, lsum = 0.f;
    f32x16 acc_o[4];
#pragma unroll
    for (int dt = 0; dt < 4; dt++)
#pragma unroll
        for (int r = 0; r < 16; r++) acc_o[dt][r] = 0.f;

    bf16x8 kst[4], vst[4];
#pragma unroll
    for (int i = 0; i < 4; i++) {
        const int s_ = i * 256 + t; const int row = s_ >> 4; const int u = s_ & 15;
        kst[i] = *(const bf16x8*)(qkv + (brow + row) * 6144 + 2048 + h * 128 + u * 8);
    }
#pragma unroll
    for (int i = 0; i < 4; i++) {
        const int s_ = i * 256 + t; const int row = s_ >> 3; const int u = s_ & 7;
        vst[i] = *(const bf16x8*)(Vt + (vbase + row) * 2048 + u * 8);
    }

    for (int s0 = 0; s0 < 2048; s0 += 64) {
        const int mk = mask[brow + s0 + l];
        const unsigned long long bm = __ballot(mk != 0);
        asm volatile("s_waitcnt lgkmcnt(0)" ::: "memory");
        asm volatile("s_barrier" ::: "memory");          // all waves done reading prev tile
#pragma unroll
        for (int i = 0; i < 4; i++) {
            const int s_ = i * 256 + t; const int row = s_ >> 4; const int u = s_ & 15;
            *(bf16x8*)(Ks + row * 128 + ((u ^ (row & 15)) << 3)) = kst[i];
        }
#pragma unroll
        for (int i = 0; i < 4; i++) {
            const int s_ = i * 256 + t; const int row = s_ >> 3; const int u = s_ & 7;
            *(bf16x8*)(Vs + row * 64 + ((u ^ (row & 7)) << 3)) = vst[i];
        }
        if (s0 + 64 < 2048) {
#pragma unroll
            for (int i = 0; i < 4; i++) {
                const int s_ = i * 256 + t; const int row = s_ >> 4; const int u = s_ & 15;
                kst[i] = *(const bf16x8*)(qkv + (brow + s0 + 64 + row) * 6144 + 2048 + h * 128 + u * 8);
            }
#pragma unroll
            for (int i = 0; i < 4; i++) {
                const int s_ = i * 256 + t; const int row = s_ >> 3; const int u = s_ & 7;
                vst[i] = *(const bf16x8*)(Vt + (vbase + row) * 2048 + s0 + 64 + u * 8);
            }
        }
        asm volatile("s_waitcnt lgkmcnt(0)" ::: "memory");  // ds_writes drained (NOT vmcnt)
        asm volatile("s_barrier" ::: "memory");             // writes visible

        f32x16 sa[2];
#pragma unroll
        for (int mt = 0; mt < 2; mt++) {
#pragma unroll
            for (int r = 0; r < 16; r++) sa[mt][r] = 0.f;
            const int row = mt * 32 + lq;
            __builtin_amdgcn_s_setprio(1);
#pragma unroll
            for (int kb = 0; kb < 8; kb++) {
                bf16x8 a = *(const bf16x8*)(Ks + row * 128 + (((kb * 2 + q2) ^ (row & 15)) << 3));
                sa[mt] = MFMA32(a, qf[kb], sa[mt]);
            }
            __builtin_amdgcn_s_setprio(0);
        }
        float p_[32];
        float mr = -1e30f;
        if (bm == ~0ull) {
#pragma unroll
            for (int mt = 0; mt < 2; mt++)
#pragma unroll
                for (int r = 0; r < 16; r++) {
                    const float v = sa[mt][r] * scale;
                    p_[mt * 16 + r] = v;
                    mr = fmaxf(mr, v);
                }
        } else {
#pragma unroll
            for (int mt = 0; mt < 2; mt++)
#pragma unroll
                for (int r = 0; r < 16; r++) {
                    const int srow = mt * 32 + (r & 3) + 8 * (r >> 2) + 4 * q2;
                    const float bias = ((bm >> srow) & 1ull) ? 0.f : -1e9f;
                    const float v = sa[mt][r] * scale + bias;
                    p_[mt * 16 + r] = v;
                    mr = fmaxf(mr, v);
                }
        }
        mr = fmaxf(mr, __shfl_xor(mr, 32, 64));
        if (!__all(mr <= m_old + 8.0f)) {        // T13 defer-max
            const float mnew = fmaxf(m_old, mr);
            const float alpha = __expf(m_old - mnew);
            lsum *= alpha;
#pragma unroll
            for (int dt = 0; dt < 4; dt++)
#pragma unroll
                for (int r = 0; r < 16; r++) acc_o[dt][r] *= alpha;
            m_old = mnew;
        }
        float rs = 0.f;
#pragma unroll
        for (int i = 0; i < 32; i++) { p_[i] = __expf(p_[i] - m_old); rs += p_[i]; }
        rs += __shfl_xor(rs, 32, 64);
        lsum += rs;

#pragma unroll
        for (int kb = 0; kb < 4; kb++) {
            const int bb = (kb >> 1) * 16 + (kb & 1) * 8;
            unsigned w01, w23, w45, w67;
            asm("v_cvt_pk_bf16_f32 %0, %1, %2" : "=v"(w01) : "v"(p_[bb + 0]), "v"(p_[bb + 1]));
            asm("v_cvt_pk_bf16_f32 %0, %1, %2" : "=v"(w23) : "v"(p_[bb + 2]), "v"(p_[bb + 3]));
            asm("v_cvt_pk_bf16_f32 %0, %1, %2" : "=v"(w45) : "v"(p_[bb + 4]), "v"(p_[bb + 5]));
            asm("v_cvt_pk_bf16_f32 %0, %1, %2" : "=v"(w67) : "v"(p_[bb + 6]), "v"(p_[bb + 7]));
            asm("v_permlane32_swap_b32 %0, %1" : "+v"(w01), "+v"(w45));
            asm("v_permlane32_swap_b32 %0, %1" : "+v"(w23), "+v"(w67));
            union { unsigned u[4]; bf16x8 v8; } pu;
            pu.u[0] = w01; pu.u[1] = w23; pu.u[2] = w45; pu.u[3] = w67;
            __builtin_amdgcn_s_setprio(1);
#pragma unroll
            for (int dt = 0; dt < 4; dt++) {
                const int row = dt * 32 + lq;
                bf16x8 va = *(const bf16x8*)(Vs + row * 64 + (((kb * 2 + q2) ^ (row & 7)) << 3));
                acc_o[dt] = MFMA32(va, pu.v8, acc_o[dt]);
            }
            __builtin_amdgcn_s_setprio(0);
        }
    }
    __syncthreads();   // all PV reads done before epilogue overlays SM
    const float inv = (lsum > 0.f) ? 1.0f / lsum : 0.f;
#pragma unroll
    for (int dt = 0; dt < 4; dt++)
#pragma unroll
        for (int r2 = 0; r2 < 4; r2++) {
            us4 ov;
#pragma unroll
            for (int j = 0; j < 4; j++) ov[j] = f2bf(acc_o[dt][r2 * 4 + j] * inv);
            const int row = w * 32 + lq;
            const int unit = dt * 4 + r2;
            *(us4*)(SM + row * 128 + ((unit ^ (row & 15)) << 3) + q2 * 4) = ov;
        }
    __syncthreads();
#pragma unroll
    for (int i = 0; i < 8; i++) {
        const int rl = i * 4 + (l >> 4), ch = l & 15;
        const int row = w * 32 + rl;
        bf16x8 vv = *(const bf16x8*)(SM + row * 128 + ((ch ^ (row & 15)) << 3));
        *(bf16x8*)(AO + (brow + qb + row) * 2048 + h * 128 + ch * 8) = vv;
    }
}

extern "C" void kernel_launch(void* const* d_in, const int* in_sizes, int n_in,
                              void* d_out, int out_size, void* d_ws, size_t ws_size,
                              hipStream_t stream)
{
    (void)in_sizes; (void)n_in; (void)out_size; (void)ws_size;
    const void* X    = d_in[0];
    const int*  mask = (const int*)d_in[1];
    const void* Wqkv = d_in[2];
    const void* bqkv = d_in[3];
    const void* Wo   = d_in[4];
    const void* bo   = d_in[5];

    int*      flag  = (int*)d_ws;
    ushort_t* Xc    = (ushort_t*)d_ws + 16;
    ushort_t* Wqkvc = Xc + 8388608;
    ushort_t* bqkvc = Wqkvc + 12582912;
    ushort_t* Woc   = bqkvc + 6144;
    ushort_t* boc   = Woc + 4194304;
    ushort_t* qkv   = boc + 2048;
    ushort_t* Vt    = Wqkvc;   // reuse: Wqkv dead after gemm1 (Vt = 8.39M ushorts)
    ushort_t* AO    = Xc;      // reuse: X dead after gemm1

    detect_kernel<<<1, 256, 0, stream>>>((const ushort_t*)Wqkv, flag);
    convert_all_kernel<<<12292, 256, 0, stream>>>(X, Wqkv, bqkv, Wo, bo,
                                                  Xc, Wqkvc, bqkvc, Woc, boc, flag);
    gemm256_bt_bias<<<dim3(6144 / 256, 4096 / 256), 512, 0, stream>>>(Xc, Wqkvc, bqkvc, qkv, 4096, 6144, 2048);
    rope_vtrans_kernel<<<5120, 256, 0, stream>>>(qkv, Vt);
    flash_kernel<<<512, 256, 0, stream>>>(qkv, Vt, mask, AO);
    gemm256_bt_bias_out<<<dim3(2048 / 256, 4096 / 256), 512, 0, stream>>>(AO, Woc, boc, d_out, 4096, 2048, 2048, flag);
}